// Round 7
// baseline (398.871 us; speedup 1.0000x reference)
//
#include <hip/hip_runtime.h>
#include <hip/hip_bf16.h>
#include <stdint.h>

#define HD 64
#define CHUNK 4096
#define EPT 16
#define USH 9            // user bucket shift
#define MSH 8            // movie bucket shift
#define FCAP 12288
#define VMASK 0x7fffffu  // low 23 bits = value; high bits = node-within-bucket
#define NREP 64          // stats replicas (contention spreading)

typedef __bf16 bf16x8 __attribute__((ext_vector_type(8)));
typedef float f32x4 __attribute__((ext_vector_type(4)));

__device__ __forceinline__ void atomAddF(float* p, float v) { unsafeAtomicAdd(p, v); }
__device__ __forceinline__ ushort f2bf(float v) {
    __hip_bfloat16 h = __float2bfloat16(v);
    return *(ushort*)&h;
}
__device__ __forceinline__ float bf2f(ushort u) {
    return __uint_as_float(((uint)u) << 16);
}
__device__ __forceinline__ uint pack2(float a, float b) {
    return (uint)f2bf(a) | ((uint)f2bf(b) << 16);
}

// ---------------- CSR build (bucket-local) ----------------

__global__ __launch_bounds__(256) void k_bucket_hist(
    const int* __restrict__ src, const int* __restrict__ dst,
    int* __restrict__ bk_u, int* __restrict__ bk_m, int E, int shu, int shm)
{
    __shared__ int hu[256], hm[256];
    int tid = threadIdx.x;
    hu[tid] = 0; hm[tid] = 0;
    __syncthreads();
    int t = blockIdx.x * 256 + tid;
    int stride = gridDim.x * 256;
    for (; t < E; t += stride) {
        atomicAdd(&hu[src[t] >> shu], 1);
        atomicAdd(&hm[dst[t] >> shm], 1);
    }
    __syncthreads();
    if (hu[tid]) atomicAdd(&bk_u[tid], hu[tid]);
    if (hm[tid]) atomicAdd(&bk_m[tid], hm[tid]);
}

__global__ void k_bucket_scan(const int* __restrict__ bk_u, const int* __restrict__ bk_m,
                              int* __restrict__ bkrp_u, int* __restrict__ bkrp_m,
                              int* __restrict__ bcur_u, int* __restrict__ bcur_m,
                              int NBu, int NBm, int E)
{
    __shared__ int sh[256];
    int t = threadIdx.x;
    int v = (t < NBu) ? bk_u[t] : 0;
    sh[t] = v; __syncthreads();
    for (int off = 1; off < 256; off <<= 1) {
        int x = (t >= off) ? sh[t - off] : 0;
        __syncthreads(); sh[t] += x; __syncthreads();
    }
    int excl = sh[t] - v;
    if (t < NBu) { bkrp_u[t] = excl; bcur_u[t] = excl; }
    if (t == NBu) bkrp_u[t] = E;
    __syncthreads();
    v = (t < NBm) ? bk_m[t] : 0;
    sh[t] = v; __syncthreads();
    for (int off = 1; off < 256; off <<= 1) {
        int x = (t >= off) ? sh[t - off] : 0;
        __syncthreads(); sh[t] += x; __syncthreads();
    }
    excl = sh[t] - v;
    if (t < NBm) { bkrp_m[t] = excl; bcur_m[t] = excl; }
    if (t == NBm) bkrp_m[t] = E;
}

__global__ __launch_bounds__(256) void k_bucket_scatter(
    const int* __restrict__ key, const int* __restrict__ val,
    int* __restrict__ bcur, uint* __restrict__ pairs, int E, int NB, int sh)
{
    __shared__ int lcnt[256], lstart[256], gbase[256];
    __shared__ uint2 lpair[CHUNK];
    int tid = threadIdx.x;
    int base = blockIdx.x * CHUNK;
    int kk[EPT], vv[EPT], ofs[EPT];
    #pragma unroll
    for (int i = 0; i < EPT; ++i) {
        int idx = base + i * 256 + tid;
        bool ok = idx < E;
        kk[i] = ok ? key[idx] : -1;
        vv[i] = ok ? val[idx] : 0;
    }
    lcnt[tid] = 0;
    __syncthreads();
    #pragma unroll
    for (int i = 0; i < EPT; ++i)
        if (kk[i] >= 0) ofs[i] = atomicAdd(&lcnt[kk[i] >> sh], 1);
    __syncthreads();
    int c = lcnt[tid];
    lstart[tid] = c;
    __syncthreads();
    for (int off = 1; off < 256; off <<= 1) {
        int x = (tid >= off) ? lstart[tid - off] : 0;
        __syncthreads(); lstart[tid] += x; __syncthreads();
    }
    lstart[tid] -= c;
    if (c > 0 && tid < NB) gbase[tid] = atomicAdd(&bcur[tid], c);
    __syncthreads();
    #pragma unroll
    for (int i = 0; i < EPT; ++i)
        if (kk[i] >= 0) {
            int b = kk[i] >> sh;
            lpair[lstart[b] + ofs[i]] = make_uint2((uint)kk[i], (uint)vv[i]);
        }
    __syncthreads();
    int total = E - base; if (total > CHUNK) total = CHUNK;
    uint bmask = (1u << sh) - 1u;
    for (int j = tid; j < total; j += 256) {
        uint2 p = lpair[j];
        int b = (int)(p.x >> sh);
        pairs[gbase[b] + (j - lstart[b])] = ((p.x & bmask) << 23) | p.y;
    }
}

__global__ __launch_bounds__(256) void k_bucket_finalize(
    const uint* __restrict__ pairs, const int* __restrict__ bkrp,
    int* __restrict__ rp, int* __restrict__ nbr, int N, int E, int sh)
{
    __shared__ int lcnt[512];
    __shared__ int lsc[256];
    __shared__ uint lp[FCAP];
    int b = blockIdx.x, tid = threadIdx.x;
    int base = b << sh;
    int rs = bkrp[b], re = bkrp[b + 1];
    int cnt = re - rs;
    bool staged = cnt <= FCAP;
    lcnt[tid] = 0; lcnt[tid + 256] = 0;
    __syncthreads();
    if (staged) {
        for (int j = tid; j < cnt; j += 256) {
            uint p = pairs[rs + j];
            lp[j] = p;
            atomicAdd(&lcnt[p >> 23], 1);
        }
    } else {
        for (int j = rs + tid; j < re; j += 256)
            atomicAdd(&lcnt[pairs[j] >> 23], 1);
    }
    __syncthreads();
    int c0 = lcnt[2 * tid], c1 = lcnt[2 * tid + 1];
    int s = c0 + c1;
    lsc[tid] = s;
    __syncthreads();
    for (int off = 1; off < 256; off <<= 1) {
        int x = (tid >= off) ? lsc[tid - off] : 0;
        __syncthreads(); lsc[tid] += x; __syncthreads();
    }
    int excl = lsc[tid] - s;
    int nbn = N - base; int bsz = 1 << sh; if (nbn > bsz) nbn = bsz;
    if (2 * tid < nbn)     rp[base + 2 * tid]     = rs + excl;
    if (2 * tid + 1 < nbn) rp[base + 2 * tid + 1] = rs + excl + c0;
    if (b == gridDim.x - 1 && tid == 0) rp[N] = E;
    lcnt[2 * tid] = excl;
    lcnt[2 * tid + 1] = excl + c0;
    __syncthreads();
    if (staged) {
        for (int j = tid; j < cnt; j += 256) {
            uint p = lp[j];
            int pos = rs + atomicAdd(&lcnt[p >> 23], 1);
            nbr[pos] = (int)(p & VMASK);
        }
    } else {
        for (int j = rs + tid; j < re; j += 256) {
            uint p = pairs[j];
            int pos = rs + atomicAdd(&lcnt[p >> 23], 1);
            nbr[pos] = (int)(p & VMASK);
        }
    }
}

// ---------------- weight fragment packing (5 matrices, one kernel) ----------------
__global__ void k_pack_all(const float* __restrict__ w0lo, const float* __restrict__ w0hi,
                           const float* __restrict__ w1lo, const float* __restrict__ w1hi,
                           const float* __restrict__ w2lo, const float* __restrict__ w2hi,
                           const float* __restrict__ w3lo, const float* __restrict__ w3hi,
                           const float* __restrict__ w4lo, const float* __restrict__ w4hi,
                           ushort* __restrict__ dst) {
    int t = blockIdx.x * blockDim.x + threadIdx.x;   // 40960 threads
    int mid = t >> 13, r = t & 8191;
    const float* lo; const float* hi;
    switch (mid) {
        case 0: lo = w0lo; hi = w0hi; break;
        case 1: lo = w1lo; hi = w1hi; break;
        case 2: lo = w2lo; hi = w2hi; break;
        case 3: lo = w3lo; hi = w3hi; break;
        default: lo = w4lo; hi = w4hi;
    }
    int e = r & 7, lane = (r >> 3) & 63, nn = (r >> 9) & 3, kk = r >> 11;
    int k = (lane >> 4) * 8 + e + 32 * kk;
    int col = (lane & 15) + 16 * nn;
    float v = (k < 64) ? lo[k * 64 + col] : hi[(k - 64) * 64 + col];
    dst[t] = f2bf(v);
}

// BN-apply on a bf16x8 fragment
template<int RELU>
__device__ __forceinline__ bf16x8 bn_frag(bf16x8 raw, const float* sc, const float* sh) {
    bf16x8 o;
    #pragma unroll
    for (int e = 0; e < 8; ++e) {
        float f = bf2f(((const ushort*)&raw)[e]);
        f = f * sc[e] + sh[e];
        if (RELU) f = fmaxf(f, 0.f);
        ((ushort*)&o)[e] = f2bf(f);
    }
    return o;
}

// ---------------- fused stage: mean-gather + MFMA + col-stats ----------------
// block = 64 dst nodes, 4 waves x 16 nodes. LDS mean tile padded to 36 uints/row.
template<int BN>
__global__ __launch_bounds__(256) void k_stage(
    const ushort* __restrict__ xsrc, const float* __restrict__ ssx,
    const ushort* __restrict__ xdst, const float* __restrict__ ssd,
    const int* __restrict__ rp, const int* __restrict__ nbr,
    const ushort* __restrict__ wp, const float* __restrict__ blv,
    ushort* __restrict__ out, float* __restrict__ stats, int N)
{
    __shared__ uint mlds[64][36];
    __shared__ float lsum[64], lsq[64];
    int tid = threadIdx.x;
    if (tid < 64) { lsum[tid] = 0.f; lsq[tid] = 0.f; }
    int wave = tid >> 6, lane = tid & 63;
    int wr0 = wave * 16;
    int n0 = blockIdx.x * 64;

    // B fragments (issued first; overlap with gather)
    const bf16x8* wpv = (const bf16x8*)wp + lane;
    bf16x8 b[4][4];
    #pragma unroll
    for (int kk = 0; kk < 4; ++kk)
        #pragma unroll
        for (int nn = 0; nn < 4; ++nn)
            b[kk][nn] = wpv[(kk * 4 + nn) * 64];

    // ---- gather/mean: 8 passes x 2 nodes per wave ----
    int c = lane & 31, sub = lane >> 5;
    float sc0 = 0.f, sc1 = 0.f, sh0 = 0.f, sh1 = 0.f;
    if (BN) {
        sc0 = ssx[2 * c]; sc1 = ssx[2 * c + 1];
        sh0 = ssx[64 + 2 * c]; sh1 = ssx[64 + 2 * c + 1];
    }
    const uint* xs = (const uint*)xsrc;
    #pragma unroll
    for (int pass = 0; pass < 8; ++pass) {
        int lr = wr0 + pass * 2 + sub;
        int node = n0 + lr;
        int cn = node < N ? node : N - 1;
        int s0 = rp[cn], s1 = rp[cn + 1];
        if (node >= N) s1 = s0;
        float a0 = 0.f, a1 = 0.f;
        int k = s0;
        for (; k + 4 <= s1; k += 4) {
            int i0 = nbr[k], i1 = nbr[k + 1], i2 = nbr[k + 2], i3 = nbr[k + 3];
            uint uu[4] = { xs[(size_t)i0 * 32 + c], xs[(size_t)i1 * 32 + c],
                           xs[(size_t)i2 * 32 + c], xs[(size_t)i3 * 32 + c] };
            #pragma unroll
            for (int i = 0; i < 4; ++i) {
                float f0 = __uint_as_float(uu[i] << 16);
                float f1 = __uint_as_float(uu[i] & 0xffff0000u);
                if (BN) { f0 = fmaxf(f0 * sc0 + sh0, 0.f); f1 = fmaxf(f1 * sc1 + sh1, 0.f); }
                a0 += f0; a1 += f1;
            }
        }
        for (; k < s1; ++k) {
            uint u = xs[(size_t)nbr[k] * 32 + c];
            float f0 = __uint_as_float(u << 16);
            float f1 = __uint_as_float(u & 0xffff0000u);
            if (BN) { f0 = fmaxf(f0 * sc0 + sh0, 0.f); f1 = fmaxf(f1 * sc1 + sh1, 0.f); }
            a0 += f0; a1 += f1;
        }
        float inv = (s1 > s0) ? 1.f / (float)(s1 - s0) : 0.f;
        mlds[lr][c] = pack2(a0 * inv, a1 * inv);
    }
    __syncthreads();

    // ---- MFMA ----
    int lrow = lane & 15, lk = lane >> 4;
    bf16x8 a[4];
    a[0] = *(const bf16x8*)&mlds[wr0 + lrow][lk * 4];        // cols lk*8..+7
    a[1] = *(const bf16x8*)&mlds[wr0 + lrow][16 + lk * 4];   // cols 32+lk*8..
    int arow = n0 + wr0 + lrow; if (arow >= N) arow = N - 1;
    const ushort* px = xdst + (size_t)arow * HD + lk * 8;
    if (BN) {
        a[2] = bn_frag<1>(*(const bf16x8*)px,        ssd + lk * 8,      ssd + 64 + lk * 8);
        a[3] = bn_frag<1>(*(const bf16x8*)(px + 32), ssd + 32 + lk * 8, ssd + 96 + lk * 8);
    } else {
        a[2] = *(const bf16x8*)px;
        a[3] = *(const bf16x8*)(px + 32);
    }

    f32x4 acc[4];
    #pragma unroll
    for (int nn = 0; nn < 4; ++nn) acc[nn] = (f32x4){0.f, 0.f, 0.f, 0.f};
    #pragma unroll
    for (int kk = 0; kk < 4; ++kk)
        #pragma unroll
        for (int nn = 0; nn < 4; ++nn)
            acc[nn] = __builtin_amdgcn_mfma_f32_16x16x32_bf16(a[kk], b[kk][nn], acc[nn], 0, 0, 0);

    int n0w = n0 + wr0;
    #pragma unroll
    for (int nn = 0; nn < 4; ++nn) {
        float bias = blv[lrow + 16 * nn];
        float s = 0.f, q = 0.f;
        #pragma unroll
        for (int r = 0; r < 4; ++r) {
            int orow = n0w + lk * 4 + r;
            float v = acc[nn][r] + bias;
            bool ok = orow < N;
            if (ok) out[(size_t)orow * HD + lrow + 16 * nn] = f2bf(v);
            float vv = ok ? v : 0.f;
            s += vv; q += vv * vv;
        }
        s += __shfl_xor(s, 16); s += __shfl_xor(s, 32);
        q += __shfl_xor(q, 16); q += __shfl_xor(q, 32);
        if (lk == 0) {
            atomAddF(&lsum[lrow + 16 * nn], s);
            atomAddF(&lsq[lrow + 16 * nn], q);
        }
    }
    __syncthreads();
    float* st = stats + (size_t)(blockIdx.x & (NREP - 1)) * 128;
    if (tid < 64) {
        atomAddF(&st[tid], lsum[tid]);
        atomAddF(&st[64 + tid], lsq[tid]);
    }
}

// reduce NREP stat replicas, then compute scale/shift. 128 threads, 1 block.
__global__ void k_bn_finalize(const float* __restrict__ stats,
                              const float* __restrict__ g, const float* __restrict__ b,
                              float* __restrict__ ss, int N)
{
    __shared__ float red[128];
    int j = threadIdx.x;   // 0..127
    float s = 0.f;
    #pragma unroll 8
    for (int r = 0; r < NREP; ++r) s += stats[r * 128 + j];
    red[j] = s;
    __syncthreads();
    if (j < HD) {
        float invN = 1.f / (float)N;
        float mu = red[j] * invN;
        float var = red[HD + j] * invN - mu * mu;
        var = var < 0.f ? 0.f : var;
        float sc = g[j] * rsqrtf(var + 1e-5f);
        ss[j] = sc;
        ss[HD + j] = b[j] - mu * sc;
    }
}

// ---------------- classifier (BN both operands, fused) ----------------
__global__ __launch_bounds__(256) void k_cls_mfma(
    const ushort* __restrict__ xu, const float* __restrict__ ssu,
    const ushort* __restrict__ xm, const float* __restrict__ ssm,
    const int* __restrict__ lsrc, const int* __restrict__ ldst,
    const ushort* __restrict__ wp, const float* __restrict__ b1,
    const float* __restrict__ w2, const float* __restrict__ b2,
    float* __restrict__ out, int L)
{
    int wave = threadIdx.x >> 6, lane = threadIdx.x & 63;
    int l0 = blockIdx.x * 64 + wave * 16;
    if (l0 >= L) return;
    int lrow = lane & 15, lk = lane >> 4;
    int li = l0 + lrow; if (li >= L) li = L - 1;
    const ushort* pu = xu + (size_t)lsrc[li] * HD + lk * 8;
    const ushort* pm = xm + (size_t)ldst[li] * HD + lk * 8;
    const bf16x8* wpv = (const bf16x8*)wp + lane;

    bf16x8 a[4];
    a[0] = bn_frag<1>(*(const bf16x8*)(pu),      ssu + lk * 8,      ssu + 64 + lk * 8);
    a[1] = bn_frag<1>(*(const bf16x8*)(pu + 32), ssu + 32 + lk * 8, ssu + 96 + lk * 8);
    a[2] = bn_frag<1>(*(const bf16x8*)(pm),      ssm + lk * 8,      ssm + 64 + lk * 8);
    a[3] = bn_frag<1>(*(const bf16x8*)(pm + 32), ssm + 32 + lk * 8, ssm + 96 + lk * 8);

    f32x4 acc[4];
    #pragma unroll
    for (int nn = 0; nn < 4; ++nn) acc[nn] = (f32x4){0.f, 0.f, 0.f, 0.f};
    #pragma unroll
    for (int kk = 0; kk < 4; ++kk)
        #pragma unroll
        for (int nn = 0; nn < 4; ++nn)
            acc[nn] = __builtin_amdgcn_mfma_f32_16x16x32_bf16(a[kk], wpv[(kk * 4 + nn) * 64], acc[nn], 0, 0, 0);

    float p0 = 0.f, p1 = 0.f, p2 = 0.f, p3 = 0.f;
    #pragma unroll
    for (int nn = 0; nn < 4; ++nn) {
        int cidx = lrow + 16 * nn;
        float bb = b1[cidx], w = w2[cidx];
        p0 += fmaxf(acc[nn][0] + bb, 0.f) * w;
        p1 += fmaxf(acc[nn][1] + bb, 0.f) * w;
        p2 += fmaxf(acc[nn][2] + bb, 0.f) * w;
        p3 += fmaxf(acc[nn][3] + bb, 0.f) * w;
    }
    #pragma unroll
    for (int off = 1; off < 16; off <<= 1) {
        p0 += __shfl_xor(p0, off);
        p1 += __shfl_xor(p1, off);
        p2 += __shfl_xor(p2, off);
        p3 += __shfl_xor(p3, off);
    }
    if (lrow == 0) {
        float bb2 = b2[0];
        int r0 = l0 + lk * 4;
        if (r0 + 0 < L) out[r0 + 0] = p0 + bb2;
        if (r0 + 1 < L) out[r0 + 1] = p1 + bb2;
        if (r0 + 2 < L) out[r0 + 2] = p2 + bb2;
        if (r0 + 3 < L) out[r0 + 3] = p3 + bb2;
    }
}

// ---------------- dense init ----------------

__global__ __launch_bounds__(256) void k_movie_feat(
    const float* __restrict__ mx, const float* __restrict__ W,
    const float* __restrict__ b, const float* __restrict__ memb,
    const int* __restrict__ mids, ushort* __restrict__ xm, int NM, int F)
{
    int m = blockIdx.x * blockDim.x + threadIdx.x;
    if (m >= NM) return;
    const float* xr = mx + (size_t)m * F;
    float acc[HD];
    #pragma unroll
    for (int j = 0; j < HD; ++j) acc[j] = b[j];
    for (int f = 0; f < F; ++f) {
        float v = xr[f];
        #pragma unroll
        for (int j = 0; j < HD; ++j) acc[j] += v * W[f * HD + j];
    }
    int nid = mids[m];
    const float* er = memb + (size_t)nid * HD;
    uint* o = (uint*)(xm + (size_t)m * HD);
    #pragma unroll
    for (int j = 0; j < HD; j += 2)
        o[j >> 1] = pack2(acc[j] + er[j], acc[j + 1] + er[j + 1]);
}

__global__ __launch_bounds__(256) void k_gather_rows(
    const float* __restrict__ src, const int* __restrict__ idx,
    ushort* __restrict__ dst, int N)
{
    int t = blockIdx.x * blockDim.x + threadIdx.x;
    int total = N * HD;
    int stride = gridDim.x * blockDim.x;
    for (; t < total; t += stride) {
        int i = t >> 6, h = t & 63;
        dst[t] = f2bf(src[(size_t)idx[i] * HD + h]);
    }
}

extern "C" void kernel_launch(void* const* d_in, const int* in_sizes, int n_in,
                              void* d_out, int out_size, void* d_ws, size_t ws_size,
                              hipStream_t stream) {
    (void)n_in; (void)ws_size;
    const int NU = in_sizes[1] / HD;
    const int NM = in_sizes[2] / HD;
    const int F  = in_sizes[0] / NM;
    const int E  = in_sizes[31];
    const int L  = out_size;
    const int NBm = (NM + (1 << MSH) - 1) >> MSH;
    const int NBu = (NU + (1 << USH) - 1) >> USH;

    int iL0RA, iL0RE, iL1RA, iL1RE, iBN0U, iBN0M, iBN1U, iBN1M;
    if (in_sizes[11] == HD) {          // setup-dict order
        iL0RA = 5; iL0RE = 8; iBN0U = 11; iBN0M = 13;
        iL1RA = 15; iL1RE = 18; iBN1U = 21; iBN1M = 23;
    } else {                           // reference-signature order
        iL0RA = 5; iL0RE = 8; iL1RA = 11; iL1RE = 14;
        iBN0U = 17; iBN0M = 19; iBN1U = 21; iBN1M = 23;
    }
    const float* movie_x   = (const float*)d_in[0];
    const float* user_emb  = (const float*)d_in[1];
    const float* movie_emb = (const float*)d_in[2];
    const float* mlw       = (const float*)d_in[3];
    const float* mlb       = (const float*)d_in[4];
    const float* cls_w1    = (const float*)d_in[25];
    const float* cls_b1    = (const float*)d_in[26];
    const float* cls_w2    = (const float*)d_in[27];
    const float* cls_b2    = (const float*)d_in[28];
    const int* user_node_id  = (const int*)d_in[29];
    const int* movie_node_id = (const int*)d_in[30];
    const int* rates_src   = (const int*)d_in[31];
    const int* rates_dst   = (const int*)d_in[32];
    const int* label_src   = (const int*)d_in[33];
    const int* label_dst   = (const int*)d_in[34];

    // ---- workspace ----
    char* wsb = (char*)d_ws;
    auto alloc = [&](size_t bytes) { char* p = wsb; wsb += (bytes + 255) & ~(size_t)255; return p; };
    ushort* xu_a = (ushort*)alloc((size_t)NU * HD * 2);
    ushort* xu_b = (ushort*)alloc((size_t)NU * HD * 2);
    ushort* xm_a = (ushort*)alloc((size_t)NM * HD * 2);
    ushort* xm_b = (ushort*)alloc((size_t)NM * HD * 2);
    ushort* wp_all = (ushort*)alloc(5 * 8192 * 2);
    int* rp_m = (int*)alloc((size_t)(NM + 1) * 4);
    int* rp_u = (int*)alloc((size_t)(NU + 1) * 4);
    int* nbr_m = (int*)alloc((size_t)E * 4);
    int* nbr_u = (int*)alloc((size_t)E * 4);
    uint* pairs = (uint*)alloc((size_t)E * 4);
    int* bkrp_m = (int*)alloc(257 * 4);
    int* bkrp_u = (int*)alloc(257 * 4);
    int* bcur_m = (int*)alloc(256 * 4);
    int* bcur_u = (int*)alloc(256 * 4);
    // zeroed region: bucket counts + 4 stages x NREP x 128 stats
    size_t zr_bytes = 2 * 256 * 4 + (size_t)4 * NREP * 128 * 4;
    char* zr = alloc(zr_bytes);
    int* bk_u = (int*)zr;
    int* bk_m = bk_u + 256;
    float* statsAll = (float*)(bk_m + 256);
    float* ss_u0 = (float*)alloc(128 * 4);
    float* ss_m0 = (float*)alloc(128 * 4);
    float* ss_u1 = (float*)alloc(128 * 4);
    float* ss_m1 = (float*)alloc(128 * 4);

    ushort* wp0 = wp_all;              // l0 rev
    ushort* wp1 = wp_all + 8192;       // l0 rates
    ushort* wp2 = wp_all + 16384;      // l1 rev
    ushort* wp3 = wp_all + 24576;      // l1 rates
    ushort* wpc = wp_all + 32768;      // classifier
    float* st0 = statsAll;
    float* st1 = statsAll + NREP * 128;
    float* st2 = statsAll + 2 * NREP * 128;
    float* st3 = statsAll + 3 * NREP * 128;

    const int sgrid = (E + CHUNK - 1) / CHUNK;

    hipMemsetAsync(zr, 0, zr_bytes, stream);
    k_pack_all<<<160, 256, 0, stream>>>(
        (const float*)d_in[iL0RE + 0], (const float*)d_in[iL0RE + 2],
        (const float*)d_in[iL0RA + 0], (const float*)d_in[iL0RA + 2],
        (const float*)d_in[iL1RE + 0], (const float*)d_in[iL1RE + 2],
        (const float*)d_in[iL1RA + 0], (const float*)d_in[iL1RA + 2],
        cls_w1, cls_w1 + 64 * 64, wp_all);

    // ---- CSR build (bucket-local; movie dir uses finer 256-node buckets) ----
    k_bucket_hist<<<1024, 256, 0, stream>>>(rates_src, rates_dst, bk_u, bk_m, E, USH, MSH);
    k_bucket_scan<<<1, 256, 0, stream>>>(bk_u, bk_m, bkrp_u, bkrp_m, bcur_u, bcur_m, NBu, NBm, E);
    k_bucket_scatter<<<sgrid, 256, 0, stream>>>(rates_dst, rates_src, bcur_m, pairs, E, NBm, MSH);
    k_bucket_finalize<<<NBm, 256, 0, stream>>>(pairs, bkrp_m, rp_m, nbr_m, NM, E, MSH);
    k_bucket_scatter<<<sgrid, 256, 0, stream>>>(rates_src, rates_dst, bcur_u, pairs, E, NBu, USH);
    k_bucket_finalize<<<NBu, 256, 0, stream>>>(pairs, bkrp_u, rp_u, nbr_u, NU, E, USH);

    // ---- init node features ----
    k_movie_feat<<<(NM + 255) / 256, 256, 0, stream>>>(movie_x, mlw, mlb, movie_emb, movie_node_id, xm_a, NM, F);
    k_gather_rows<<<2048, 256, 0, stream>>>(user_emb, user_node_id, xu_a, NU);

    // ---- stage 0: user <- rev(movie) ----
    k_stage<0><<<(NU + 63) / 64, 256, 0, stream>>>(xm_a, nullptr, xu_a, nullptr,
        rp_u, nbr_u, wp0, (const float*)d_in[iL0RE + 1], xu_b, st0, NU);
    k_bn_finalize<<<1, 128, 0, stream>>>(st0, (const float*)d_in[iBN0U], (const float*)d_in[iBN0U + 1], ss_u0, NU);
    // ---- stage 1: movie <- rates(user) ----
    k_stage<0><<<(NM + 63) / 64, 256, 0, stream>>>(xu_a, nullptr, xm_a, nullptr,
        rp_m, nbr_m, wp1, (const float*)d_in[iL0RA + 1], xm_b, st1, NM);
    k_bn_finalize<<<1, 128, 0, stream>>>(st1, (const float*)d_in[iBN0M], (const float*)d_in[iBN0M + 1], ss_m0, NM);
    // ---- stage 2: user layer 1 ----
    k_stage<1><<<(NU + 63) / 64, 256, 0, stream>>>(xm_b, ss_m0, xu_b, ss_u0,
        rp_u, nbr_u, wp2, (const float*)d_in[iL1RE + 1], xu_a, st2, NU);
    k_bn_finalize<<<1, 128, 0, stream>>>(st2, (const float*)d_in[iBN1U], (const float*)d_in[iBN1U + 1], ss_u1, NU);
    // ---- stage 3: movie layer 1 ----
    k_stage<1><<<(NM + 63) / 64, 256, 0, stream>>>(xu_b, ss_u0, xm_b, ss_m0,
        rp_m, nbr_m, wp3, (const float*)d_in[iL1RA + 1], xm_a, st3, NM);
    k_bn_finalize<<<1, 128, 0, stream>>>(st3, (const float*)d_in[iBN1M], (const float*)d_in[iBN1M + 1], ss_m1, NM);

    // ---- classifier ----
    k_cls_mfma<<<(L + 63) / 64, 256, 0, stream>>>(xu_a, ss_u1, xm_a, ss_m1,
        label_src, label_dst, wpc, cls_b1, cls_w2, cls_b2, (float*)d_out, L);
}

// Round 8
// 284.655 us; speedup vs baseline: 1.4012x; 1.4012x over previous
//
#include <hip/hip_runtime.h>
#include <hip/hip_bf16.h>
#include <stdint.h>

#define HD 64
#define CHUNK 4096
#define EPT 16
#define USH 9            // user bucket shift (512-node buckets)
#define MSH 8            // movie bucket shift (256-node buckets)
#define FCAP 12288
#define VMASK 0x7fffffu  // low 23 bits = value; high bits = node-within-bucket
#define NREP 64          // stats replicas (contention spreading)

typedef __bf16 bf16x8 __attribute__((ext_vector_type(8)));
typedef float f32x4 __attribute__((ext_vector_type(4)));

__device__ __forceinline__ void atomAddF(float* p, float v) { unsafeAtomicAdd(p, v); }
__device__ __forceinline__ ushort f2bf(float v) {
    __hip_bfloat16 h = __float2bfloat16(v);
    return *(ushort*)&h;
}
__device__ __forceinline__ float bf2f(ushort u) {
    return __uint_as_float(((uint)u) << 16);
}
__device__ __forceinline__ uint pack2(float a, float b) {
    return (uint)f2bf(a) | ((uint)f2bf(b) << 16);
}

// ---------------- CSR build (bucket-local) ----------------

__global__ __launch_bounds__(256) void k_bucket_hist(
    const int* __restrict__ src, const int* __restrict__ dst,
    int* __restrict__ bk_u, int* __restrict__ bk_m, int E)
{
    __shared__ int hu[256], hm[256];
    int tid = threadIdx.x;
    hu[tid] = 0; hm[tid] = 0;
    __syncthreads();
    int t = blockIdx.x * 256 + tid;
    int stride = gridDim.x * 256;
    for (; t < E; t += stride) {
        atomicAdd(&hu[src[t] >> USH], 1);
        atomicAdd(&hm[dst[t] >> MSH], 1);
    }
    __syncthreads();
    if (hu[tid]) atomicAdd(&bk_u[tid], hu[tid]);
    if (hm[tid]) atomicAdd(&bk_m[tid], hm[tid]);
}

__global__ void k_bucket_scan(const int* __restrict__ bk_u, const int* __restrict__ bk_m,
                              int* __restrict__ bkrp_u, int* __restrict__ bkrp_m,
                              int* __restrict__ bcur_u, int* __restrict__ bcur_m,
                              int NBu, int NBm, int E)
{
    __shared__ int sh[256];
    int t = threadIdx.x;
    int v = (t < NBu) ? bk_u[t] : 0;
    sh[t] = v; __syncthreads();
    for (int off = 1; off < 256; off <<= 1) {
        int x = (t >= off) ? sh[t - off] : 0;
        __syncthreads(); sh[t] += x; __syncthreads();
    }
    int excl = sh[t] - v;
    if (t < NBu) { bkrp_u[t] = excl; bcur_u[t] = excl; }
    if (t == NBu) bkrp_u[t] = E;
    __syncthreads();
    v = (t < NBm) ? bk_m[t] : 0;
    sh[t] = v; __syncthreads();
    for (int off = 1; off < 256; off <<= 1) {
        int x = (t >= off) ? sh[t - off] : 0;
        __syncthreads(); sh[t] += x; __syncthreads();
    }
    excl = sh[t] - v;
    if (t < NBm) { bkrp_m[t] = excl; bcur_m[t] = excl; }
    if (t == NBm) bkrp_m[t] = E;
}

// one phase of the dual scatter (keys/vals already in registers)
__device__ __forceinline__ void scatter_phase(
    const int* kk, const int* vv, int sh, int NB,
    int* __restrict__ bcur, uint* __restrict__ pairs, int E, int base, int tid,
    int* lcnt, int* lstart, int* gbase, uint2* lpair)
{
    lcnt[tid] = 0;
    __syncthreads();
    int ofs[EPT];
    #pragma unroll
    for (int i = 0; i < EPT; ++i)
        if (kk[i] >= 0) ofs[i] = atomicAdd(&lcnt[kk[i] >> sh], 1);
    __syncthreads();
    int c = lcnt[tid];
    lstart[tid] = c;
    __syncthreads();
    for (int off = 1; off < 256; off <<= 1) {
        int x = (tid >= off) ? lstart[tid - off] : 0;
        __syncthreads(); lstart[tid] += x; __syncthreads();
    }
    lstart[tid] -= c;
    if (c > 0 && tid < NB) gbase[tid] = atomicAdd(&bcur[tid], c);
    __syncthreads();
    #pragma unroll
    for (int i = 0; i < EPT; ++i)
        if (kk[i] >= 0) {
            int b = kk[i] >> sh;
            lpair[lstart[b] + ofs[i]] = make_uint2((uint)kk[i], (uint)vv[i]);
        }
    __syncthreads();
    int total = E - base; if (total > CHUNK) total = CHUNK;
    uint bmask = (1u << sh) - 1u;
    for (int j = tid; j < total; j += 256) {
        uint2 p = lpair[j];
        int b = (int)(p.x >> sh);
        pairs[gbase[b] + (j - lstart[b])] = ((p.x & bmask) << 23) | p.y;
    }
}

// dual-direction scatter: load (src,dst) once, bucket both ways
__global__ __launch_bounds__(256) void k_scatter2(
    const int* __restrict__ srcA, const int* __restrict__ dstA,
    int* __restrict__ bcur_m, uint* __restrict__ pairs_m,
    int* __restrict__ bcur_u, uint* __restrict__ pairs_u,
    int E, int NBm, int NBu)
{
    __shared__ int lcnt[256], lstart[256], gbase[256];
    __shared__ uint2 lpair[CHUNK];
    int tid = threadIdx.x;
    int base = blockIdx.x * CHUNK;
    int ssr[EPT], ddr[EPT];
    #pragma unroll
    for (int i = 0; i < EPT; ++i) {
        int idx = base + i * 256 + tid;
        bool ok = idx < E;
        ssr[i] = ok ? srcA[idx] : -1;
        ddr[i] = ok ? dstA[idx] : -1;
    }
    // movie-dst direction: key=dst, val=src
    scatter_phase(ddr, ssr, MSH, NBm, bcur_m, pairs_m, E, base, tid, lcnt, lstart, gbase, lpair);
    __syncthreads();
    // user-dst direction: key=src, val=dst
    scatter_phase(ssr, ddr, USH, NBu, bcur_u, pairs_u, E, base, tid, lcnt, lstart, gbase, lpair);
}

__device__ __forceinline__ void finalize_body(
    const uint* __restrict__ pairs, const int* __restrict__ bkrp,
    int* __restrict__ rp, int* __restrict__ nbr,
    int N, int E, int sh, int b, int NB, int tid,
    int* lcnt, int* lsc, uint* lp)
{
    int base = b << sh;
    int rs = bkrp[b], re = bkrp[b + 1];
    int cnt = re - rs;
    bool staged = cnt <= FCAP;
    lcnt[tid] = 0; lcnt[tid + 256] = 0;
    __syncthreads();
    if (staged) {
        for (int j = tid; j < cnt; j += 256) {
            uint p = pairs[rs + j];
            lp[j] = p;
            atomicAdd(&lcnt[p >> 23], 1);
        }
    } else {
        for (int j = rs + tid; j < re; j += 256)
            atomicAdd(&lcnt[pairs[j] >> 23], 1);
    }
    __syncthreads();
    int c0 = lcnt[2 * tid], c1 = lcnt[2 * tid + 1];
    int s = c0 + c1;
    lsc[tid] = s;
    __syncthreads();
    for (int off = 1; off < 256; off <<= 1) {
        int x = (tid >= off) ? lsc[tid - off] : 0;
        __syncthreads(); lsc[tid] += x; __syncthreads();
    }
    int excl = lsc[tid] - s;
    int nbn = N - base; int bsz = 1 << sh; if (nbn > bsz) nbn = bsz;
    if (2 * tid < nbn)     rp[base + 2 * tid]     = rs + excl;
    if (2 * tid + 1 < nbn) rp[base + 2 * tid + 1] = rs + excl + c0;
    if (b == NB - 1 && tid == 0) rp[N] = E;
    lcnt[2 * tid] = excl;
    lcnt[2 * tid + 1] = excl + c0;
    __syncthreads();
    if (staged) {
        for (int j = tid; j < cnt; j += 256) {
            uint p = lp[j];
            int pos = rs + atomicAdd(&lcnt[p >> 23], 1);
            nbr[pos] = (int)(p & VMASK);
        }
    } else {
        for (int j = rs + tid; j < re; j += 256) {
            uint p = pairs[j];
            int pos = rs + atomicAdd(&lcnt[p >> 23], 1);
            nbr[pos] = (int)(p & VMASK);
        }
    }
}

// combined finalize for both directions: blocks [0,NBm) movie, [NBm, NBm+NBu) user
__global__ __launch_bounds__(256) void k_finalize2(
    const uint* __restrict__ pairs_m, const int* __restrict__ bkrp_m,
    int* __restrict__ rp_m, int* __restrict__ nbr_m, int NM, int NBm,
    const uint* __restrict__ pairs_u, const int* __restrict__ bkrp_u,
    int* __restrict__ rp_u, int* __restrict__ nbr_u, int NU, int NBu, int E)
{
    __shared__ int lcnt[512];
    __shared__ int lsc[256];
    __shared__ uint lp[FCAP];
    int b = blockIdx.x, tid = threadIdx.x;
    if (b < NBm)
        finalize_body(pairs_m, bkrp_m, rp_m, nbr_m, NM, E, MSH, b, NBm, tid, lcnt, lsc, lp);
    else
        finalize_body(pairs_u, bkrp_u, rp_u, nbr_u, NU, E, USH, b - NBm, NBu, tid, lcnt, lsc, lp);
}

// ---------------- weight fragment packing (5 matrices, one kernel) ----------------
__global__ void k_pack_all(const float* __restrict__ w0lo, const float* __restrict__ w0hi,
                           const float* __restrict__ w1lo, const float* __restrict__ w1hi,
                           const float* __restrict__ w2lo, const float* __restrict__ w2hi,
                           const float* __restrict__ w3lo, const float* __restrict__ w3hi,
                           const float* __restrict__ w4lo, const float* __restrict__ w4hi,
                           ushort* __restrict__ dst) {
    int t = blockIdx.x * blockDim.x + threadIdx.x;   // 40960 threads
    int mid = t >> 13, r = t & 8191;
    const float* lo; const float* hi;
    switch (mid) {
        case 0: lo = w0lo; hi = w0hi; break;
        case 1: lo = w1lo; hi = w1hi; break;
        case 2: lo = w2lo; hi = w2hi; break;
        case 3: lo = w3lo; hi = w3hi; break;
        default: lo = w4lo; hi = w4hi;
    }
    int e = r & 7, lane = (r >> 3) & 63, nn = (r >> 9) & 3, kk = r >> 11;
    int k = (lane >> 4) * 8 + e + 32 * kk;
    int col = (lane & 15) + 16 * nn;
    float v = (k < 64) ? lo[k * 64 + col] : hi[(k - 64) * 64 + col];
    dst[t] = f2bf(v);
}

// ---------------- combined init: movie_feat blocks then gather_rows blocks ----------------
__global__ __launch_bounds__(256) void k_init2(
    const float* __restrict__ mx, const float* __restrict__ W,
    const float* __restrict__ b, const float* __restrict__ memb,
    const int* __restrict__ mids, ushort* __restrict__ xm, int NM, int F, int gridMF,
    const float* __restrict__ uemb, const int* __restrict__ uids,
    ushort* __restrict__ xu, int NU)
{
    if ((int)blockIdx.x < gridMF) {
        int m = blockIdx.x * 256 + threadIdx.x;
        if (m >= NM) return;
        const float* xr = mx + (size_t)m * F;
        float acc[HD];
        #pragma unroll
        for (int j = 0; j < HD; ++j) acc[j] = b[j];
        for (int f = 0; f < F; ++f) {
            float v = xr[f];
            #pragma unroll
            for (int j = 0; j < HD; ++j) acc[j] += v * W[f * HD + j];
        }
        int nid = mids[m];
        const float* er = memb + (size_t)nid * HD;
        uint* o = (uint*)(xm + (size_t)m * HD);
        #pragma unroll
        for (int j = 0; j < HD; j += 2)
            o[j >> 1] = pack2(acc[j] + er[j], acc[j + 1] + er[j + 1]);
    } else {
        int t = (blockIdx.x - gridMF) * 256 + threadIdx.x;
        int total = NU * HD;
        int stride = (gridDim.x - gridMF) * 256;
        for (; t < total; t += stride) {
            int i = t >> 6, h = t & 63;
            xu[t] = f2bf(uemb[(size_t)uids[i] * HD + h]);
        }
    }
}

// ---------------- combined segmented mean (both directions, unroll 8) ----------------
template<int BN>
__global__ __launch_bounds__(256) void k_reduce2(
    const ushort* __restrict__ xsU, const float* __restrict__ ssU,
    const int* __restrict__ rpU, const int* __restrict__ nbrU,
    ushort* __restrict__ meanU, int NU, int gridU,
    const ushort* __restrict__ xsM, const float* __restrict__ ssM,
    const int* __restrict__ rpM, const int* __restrict__ nbrM,
    ushort* __restrict__ meanM, int NM)
{
    int bid = blockIdx.x;
    const ushort* xsrc; const float* ssx; const int* rp; const int* nbr; ushort* mean; int N; int sb;
    if (bid < gridU) { xsrc = xsU; ssx = ssU; rp = rpU; nbr = nbrU; mean = meanU; N = NU; sb = bid; }
    else             { xsrc = xsM; ssx = ssM; rp = rpM; nbr = nbrM; mean = meanM; N = NM; sb = bid - gridU; }
    int slot = sb * 8 + (threadIdx.x >> 5);
    if (slot >= N) return;
    int c = threadIdx.x & 31;
    float sc0 = 0.f, sc1 = 0.f, sh0 = 0.f, sh1 = 0.f;
    if (BN) {
        sc0 = ssx[2 * c]; sc1 = ssx[2 * c + 1];
        sh0 = ssx[64 + 2 * c]; sh1 = ssx[64 + 2 * c + 1];
    }
    const uint* xs = (const uint*)xsrc;
    int s0 = rp[slot], s1 = rp[slot + 1];
    float a0 = 0.f, a1 = 0.f;
    int k = s0;
    for (; k + 8 <= s1; k += 8) {
        uint uu[8];
        #pragma unroll
        for (int i = 0; i < 8; ++i) uu[i] = xs[(size_t)nbr[k + i] * 32 + c];
        #pragma unroll
        for (int i = 0; i < 8; ++i) {
            float f0 = __uint_as_float(uu[i] << 16);
            float f1 = __uint_as_float(uu[i] & 0xffff0000u);
            if (BN) { f0 = fmaxf(f0 * sc0 + sh0, 0.f); f1 = fmaxf(f1 * sc1 + sh1, 0.f); }
            a0 += f0; a1 += f1;
        }
    }
    for (; k < s1; ++k) {
        uint u = xs[(size_t)nbr[k] * 32 + c];
        float f0 = __uint_as_float(u << 16);
        float f1 = __uint_as_float(u & 0xffff0000u);
        if (BN) { f0 = fmaxf(f0 * sc0 + sh0, 0.f); f1 = fmaxf(f1 * sc1 + sh1, 0.f); }
        a0 += f0; a1 += f1;
    }
    float inv = (s1 > s0) ? 1.f / (float)(s1 - s0) : 0.f;
    ((uint*)mean)[(size_t)slot * 32 + c] = pack2(a0 * inv, a1 * inv);
}

// BN-apply on a bf16x8 fragment
template<int RELU>
__device__ __forceinline__ bf16x8 bn_frag(bf16x8 raw, const float* sc, const float* sh) {
    bf16x8 o;
    #pragma unroll
    for (int e = 0; e < 8; ++e) {
        float f = bf2f(((const ushort*)&raw)[e]);
        f = f * sc[e] + sh[e];
        if (RELU) f = fmaxf(f, 0.f);
        ((ushort*)&o)[e] = f2bf(f);
    }
    return o;
}

__device__ __forceinline__ void mfma_body(
    const ushort* __restrict__ meanb, const ushort* __restrict__ xdst,
    const float* __restrict__ ssd, const ushort* __restrict__ wp,
    const float* __restrict__ blv, ushort* __restrict__ out,
    float* __restrict__ stats, int N, int blk, int tid, int BN,
    float* lsum, float* lsq)
{
    if (tid < 64) { lsum[tid] = 0.f; lsq[tid] = 0.f; }
    __syncthreads();
    int wave = tid >> 6, lane = tid & 63;
    int n0 = blk * 64 + wave * 16;
    int lrow = lane & 15, lk = lane >> 4;
    int arow = n0 + lrow; if (arow >= N) arow = N - 1;
    const ushort* pm = meanb + (size_t)arow * HD + lk * 8;
    const ushort* px = xdst  + (size_t)arow * HD + lk * 8;
    const bf16x8* wpv = (const bf16x8*)wp + lane;

    bf16x8 b[4][4];
    #pragma unroll
    for (int kk = 0; kk < 4; ++kk)
        #pragma unroll
        for (int nn = 0; nn < 4; ++nn)
            b[kk][nn] = wpv[(kk * 4 + nn) * 64];

    bf16x8 a[4];
    a[0] = *(const bf16x8*)(pm);
    a[1] = *(const bf16x8*)(pm + 32);
    if (BN) {
        a[2] = bn_frag<1>(*(const bf16x8*)(px),      ssd + lk * 8,      ssd + 64 + lk * 8);
        a[3] = bn_frag<1>(*(const bf16x8*)(px + 32), ssd + 32 + lk * 8, ssd + 96 + lk * 8);
    } else {
        a[2] = *(const bf16x8*)(px);
        a[3] = *(const bf16x8*)(px + 32);
    }

    f32x4 acc[4];
    #pragma unroll
    for (int nn = 0; nn < 4; ++nn) acc[nn] = (f32x4){0.f, 0.f, 0.f, 0.f};
    #pragma unroll
    for (int kk = 0; kk < 4; ++kk)
        #pragma unroll
        for (int nn = 0; nn < 4; ++nn)
            acc[nn] = __builtin_amdgcn_mfma_f32_16x16x32_bf16(a[kk], b[kk][nn], acc[nn], 0, 0, 0);

    #pragma unroll
    for (int nn = 0; nn < 4; ++nn) {
        float bias = blv[lrow + 16 * nn];
        float s = 0.f, q = 0.f;
        #pragma unroll
        for (int r = 0; r < 4; ++r) {
            int orow = n0 + lk * 4 + r;
            float v = acc[nn][r] + bias;
            bool ok = orow < N;
            if (ok) out[(size_t)orow * HD + lrow + 16 * nn] = f2bf(v);
            float vv = ok ? v : 0.f;
            s += vv; q += vv * vv;
        }
        s += __shfl_xor(s, 16); s += __shfl_xor(s, 32);
        q += __shfl_xor(q, 16); q += __shfl_xor(q, 32);
        if (lk == 0) {
            atomAddF(&lsum[lrow + 16 * nn], s);
            atomAddF(&lsq[lrow + 16 * nn], q);
        }
    }
    __syncthreads();
    float* st = stats + (size_t)(blk & (NREP - 1)) * 128;
    if (tid < 64) {
        atomAddF(&st[tid], lsum[tid]);
        atomAddF(&st[64 + tid], lsq[tid]);
    }
}

// combined MFMA for both directions of a layer
template<int BN>
__global__ __launch_bounds__(256) void k_mfma2(
    const ushort* __restrict__ meanU, const ushort* __restrict__ xuD,
    const float* __restrict__ ssdU, const ushort* __restrict__ wpU,
    const float* __restrict__ blU, ushort* __restrict__ outU,
    float* __restrict__ stU, int NU, int gridU,
    const ushort* __restrict__ meanM, const ushort* __restrict__ xmD,
    const float* __restrict__ ssdM, const ushort* __restrict__ wpM,
    const float* __restrict__ blM, ushort* __restrict__ outM,
    float* __restrict__ stM, int NM)
{
    __shared__ float lsum[64], lsq[64];
    int bid = blockIdx.x, tid = threadIdx.x;
    if (bid < gridU)
        mfma_body(meanU, xuD, ssdU, wpU, blU, outU, stU, NU, bid, tid, BN, lsum, lsq);
    else
        mfma_body(meanM, xmD, ssdM, wpM, blM, outM, stM, NM, bid - gridU, tid, BN, lsum, lsq);
}

// combined BN finalize: block 0 = user, block 1 = movie
__global__ void k_bnfin2(const float* __restrict__ stA, const float* __restrict__ gA,
                         const float* __restrict__ bA, float* __restrict__ ssA, int NA,
                         const float* __restrict__ stB, const float* __restrict__ gB,
                         const float* __restrict__ bB, float* __restrict__ ssB, int NB_)
{
    __shared__ float red[128];
    const float* stats; const float* g; const float* b; float* ss; int N;
    if (blockIdx.x == 0) { stats = stA; g = gA; b = bA; ss = ssA; N = NA; }
    else                 { stats = stB; g = gB; b = bB; ss = ssB; N = NB_; }
    int j = threadIdx.x;   // 0..127
    float s = 0.f;
    #pragma unroll 8
    for (int r = 0; r < NREP; ++r) s += stats[r * 128 + j];
    red[j] = s;
    __syncthreads();
    if (j < HD) {
        float invN = 1.f / (float)N;
        float mu = red[j] * invN;
        float var = red[HD + j] * invN - mu * mu;
        var = var < 0.f ? 0.f : var;
        float sc = g[j] * rsqrtf(var + 1e-5f);
        ss[j] = sc;
        ss[HD + j] = b[j] - mu * sc;
    }
}

// ---------------- classifier (BN both operands, fused) ----------------
__global__ __launch_bounds__(256) void k_cls_mfma(
    const ushort* __restrict__ xu, const float* __restrict__ ssu,
    const ushort* __restrict__ xm, const float* __restrict__ ssm,
    const int* __restrict__ lsrc, const int* __restrict__ ldst,
    const ushort* __restrict__ wp, const float* __restrict__ b1,
    const float* __restrict__ w2, const float* __restrict__ b2,
    float* __restrict__ out, int L)
{
    int wave = threadIdx.x >> 6, lane = threadIdx.x & 63;
    int l0 = blockIdx.x * 64 + wave * 16;
    if (l0 >= L) return;
    int lrow = lane & 15, lk = lane >> 4;
    int li = l0 + lrow; if (li >= L) li = L - 1;
    const ushort* pu = xu + (size_t)lsrc[li] * HD + lk * 8;
    const ushort* pm = xm + (size_t)ldst[li] * HD + lk * 8;
    const bf16x8* wpv = (const bf16x8*)wp + lane;

    bf16x8 a[4];
    a[0] = bn_frag<1>(*(const bf16x8*)(pu),      ssu + lk * 8,      ssu + 64 + lk * 8);
    a[1] = bn_frag<1>(*(const bf16x8*)(pu + 32), ssu + 32 + lk * 8, ssu + 96 + lk * 8);
    a[2] = bn_frag<1>(*(const bf16x8*)(pm),      ssm + lk * 8,      ssm + 64 + lk * 8);
    a[3] = bn_frag<1>(*(const bf16x8*)(pm + 32), ssm + 32 + lk * 8, ssm + 96 + lk * 8);

    f32x4 acc[4];
    #pragma unroll
    for (int nn = 0; nn < 4; ++nn) acc[nn] = (f32x4){0.f, 0.f, 0.f, 0.f};
    #pragma unroll
    for (int kk = 0; kk < 4; ++kk)
        #pragma unroll
        for (int nn = 0; nn < 4; ++nn)
            acc[nn] = __builtin_amdgcn_mfma_f32_16x16x32_bf16(a[kk], wpv[(kk * 4 + nn) * 64], acc[nn], 0, 0, 0);

    float p0 = 0.f, p1 = 0.f, p2 = 0.f, p3 = 0.f;
    #pragma unroll
    for (int nn = 0; nn < 4; ++nn) {
        int cidx = lrow + 16 * nn;
        float bb = b1[cidx], w = w2[cidx];
        p0 += fmaxf(acc[nn][0] + bb, 0.f) * w;
        p1 += fmaxf(acc[nn][1] + bb, 0.f) * w;
        p2 += fmaxf(acc[nn][2] + bb, 0.f) * w;
        p3 += fmaxf(acc[nn][3] + bb, 0.f) * w;
    }
    #pragma unroll
    for (int off = 1; off < 16; off <<= 1) {
        p0 += __shfl_xor(p0, off);
        p1 += __shfl_xor(p1, off);
        p2 += __shfl_xor(p2, off);
        p3 += __shfl_xor(p3, off);
    }
    if (lrow == 0) {
        float bb2 = b2[0];
        int r0 = l0 + lk * 4;
        if (r0 + 0 < L) out[r0 + 0] = p0 + bb2;
        if (r0 + 1 < L) out[r0 + 1] = p1 + bb2;
        if (r0 + 2 < L) out[r0 + 2] = p2 + bb2;
        if (r0 + 3 < L) out[r0 + 3] = p3 + bb2;
    }
}

extern "C" void kernel_launch(void* const* d_in, const int* in_sizes, int n_in,
                              void* d_out, int out_size, void* d_ws, size_t ws_size,
                              hipStream_t stream) {
    (void)n_in; (void)ws_size;
    const int NU = in_sizes[1] / HD;
    const int NM = in_sizes[2] / HD;
    const int F  = in_sizes[0] / NM;
    const int E  = in_sizes[31];
    const int L  = out_size;
    const int NBm = (NM + (1 << MSH) - 1) >> MSH;
    const int NBu = (NU + (1 << USH) - 1) >> USH;

    int iL0RA, iL0RE, iL1RA, iL1RE, iBN0U, iBN0M, iBN1U, iBN1M;
    if (in_sizes[11] == HD) {          // setup-dict order
        iL0RA = 5; iL0RE = 8; iBN0U = 11; iBN0M = 13;
        iL1RA = 15; iL1RE = 18; iBN1U = 21; iBN1M = 23;
    } else {                           // reference-signature order
        iL0RA = 5; iL0RE = 8; iL1RA = 11; iL1RE = 14;
        iBN0U = 17; iBN0M = 19; iBN1U = 21; iBN1M = 23;
    }
    const float* movie_x   = (const float*)d_in[0];
    const float* user_emb  = (const float*)d_in[1];
    const float* movie_emb = (const float*)d_in[2];
    const float* mlw       = (const float*)d_in[3];
    const float* mlb       = (const float*)d_in[4];
    const float* cls_w1    = (const float*)d_in[25];
    const float* cls_b1    = (const float*)d_in[26];
    const float* cls_w2    = (const float*)d_in[27];
    const float* cls_b2    = (const float*)d_in[28];
    const int* user_node_id  = (const int*)d_in[29];
    const int* movie_node_id = (const int*)d_in[30];
    const int* rates_src   = (const int*)d_in[31];
    const int* rates_dst   = (const int*)d_in[32];
    const int* label_src   = (const int*)d_in[33];
    const int* label_dst   = (const int*)d_in[34];

    // ---- workspace ----
    char* wsb = (char*)d_ws;
    auto alloc = [&](size_t bytes) { char* p = wsb; wsb += (bytes + 255) & ~(size_t)255; return p; };
    ushort* xu_a = (ushort*)alloc((size_t)NU * HD * 2);
    ushort* xu_b = (ushort*)alloc((size_t)NU * HD * 2);
    ushort* xm_a = (ushort*)alloc((size_t)NM * HD * 2);
    ushort* xm_b = (ushort*)alloc((size_t)NM * HD * 2);
    ushort* meanU = (ushort*)alloc((size_t)NU * HD * 2);
    ushort* meanM = (ushort*)alloc((size_t)NM * HD * 2);
    ushort* wp_all = (ushort*)alloc(5 * 8192 * 2);
    int* rp_m = (int*)alloc((size_t)(NM + 1) * 4);
    int* rp_u = (int*)alloc((size_t)(NU + 1) * 4);
    int* nbr_m = (int*)alloc((size_t)E * 4);
    int* nbr_u = (int*)alloc((size_t)E * 4);
    uint* pairs_m = (uint*)alloc((size_t)E * 4);
    uint* pairs_u = (uint*)alloc((size_t)E * 4);
    int* bkrp_m = (int*)alloc(257 * 4);
    int* bkrp_u = (int*)alloc(257 * 4);
    int* bcur_m = (int*)alloc(256 * 4);
    int* bcur_u = (int*)alloc(256 * 4);
    // zeroed region: bucket counts + 4 stages x NREP x 128 stats
    size_t zr_bytes = 2 * 256 * 4 + (size_t)4 * NREP * 128 * 4;
    char* zr = alloc(zr_bytes);
    int* bk_u = (int*)zr;
    int* bk_m = bk_u + 256;
    float* statsAll = (float*)(bk_m + 256);
    float* ss_u0 = (float*)alloc(128 * 4);
    float* ss_m0 = (float*)alloc(128 * 4);
    float* ss_u1 = (float*)alloc(128 * 4);
    float* ss_m1 = (float*)alloc(128 * 4);

    ushort* wp0 = wp_all;              // l0 rev (user stage)
    ushort* wp1 = wp_all + 8192;       // l0 rates (movie stage)
    ushort* wp2 = wp_all + 16384;      // l1 rev
    ushort* wp3 = wp_all + 24576;      // l1 rates
    ushort* wpc = wp_all + 32768;      // classifier
    float* st0 = statsAll;
    float* st1 = statsAll + NREP * 128;
    float* st2 = statsAll + 2 * NREP * 128;
    float* st3 = statsAll + 3 * NREP * 128;

    const int sgrid = (E + CHUNK - 1) / CHUNK;
    const int gridU_r = (NU + 7) / 8,  gridM_r = (NM + 7) / 8;
    const int gridU_m = (NU + 63) / 64, gridM_m = (NM + 63) / 64;
    const int gridMF = (NM + 255) / 256;

    hipMemsetAsync(zr, 0, zr_bytes, stream);
    k_pack_all<<<160, 256, 0, stream>>>(
        (const float*)d_in[iL0RE + 0], (const float*)d_in[iL0RE + 2],
        (const float*)d_in[iL0RA + 0], (const float*)d_in[iL0RA + 2],
        (const float*)d_in[iL1RE + 0], (const float*)d_in[iL1RE + 2],
        (const float*)d_in[iL1RA + 0], (const float*)d_in[iL1RA + 2],
        cls_w1, cls_w1 + 64 * 64, wp_all);

    // ---- CSR build (dual-direction, bucket-local) ----
    k_bucket_hist<<<1024, 256, 0, stream>>>(rates_src, rates_dst, bk_u, bk_m, E);
    k_bucket_scan<<<1, 256, 0, stream>>>(bk_u, bk_m, bkrp_u, bkrp_m, bcur_u, bcur_m, NBu, NBm, E);
    k_scatter2<<<sgrid, 256, 0, stream>>>(rates_src, rates_dst, bcur_m, pairs_m, bcur_u, pairs_u, E, NBm, NBu);
    k_finalize2<<<NBm + NBu, 256, 0, stream>>>(pairs_m, bkrp_m, rp_m, nbr_m, NM, NBm,
                                               pairs_u, bkrp_u, rp_u, nbr_u, NU, NBu, E);

    // ---- init node features ----
    k_init2<<<gridMF + 2048, 256, 0, stream>>>(movie_x, mlw, mlb, movie_emb, movie_node_id,
                                               xm_a, NM, F, gridMF, user_emb, user_node_id, xu_a, NU);

    // ---- layer 0 ----
    k_reduce2<0><<<gridU_r + gridM_r, 256, 0, stream>>>(
        xm_a, nullptr, rp_u, nbr_u, meanU, NU, gridU_r,
        xu_a, nullptr, rp_m, nbr_m, meanM, NM);
    k_mfma2<0><<<gridU_m + gridM_m, 256, 0, stream>>>(
        meanU, xu_a, nullptr, wp0, (const float*)d_in[iL0RE + 1], xu_b, st0, NU, gridU_m,
        meanM, xm_a, nullptr, wp1, (const float*)d_in[iL0RA + 1], xm_b, st1, NM);
    k_bnfin2<<<2, 128, 0, stream>>>(
        st0, (const float*)d_in[iBN0U], (const float*)d_in[iBN0U + 1], ss_u0, NU,
        st1, (const float*)d_in[iBN0M], (const float*)d_in[iBN0M + 1], ss_m0, NM);

    // ---- layer 1 ----
    k_reduce2<1><<<gridU_r + gridM_r, 256, 0, stream>>>(
        xm_b, ss_m0, rp_u, nbr_u, meanU, NU, gridU_r,
        xu_b, ss_u0, rp_m, nbr_m, meanM, NM);
    k_mfma2<1><<<gridU_m + gridM_m, 256, 0, stream>>>(
        meanU, xu_b, ss_u0, wp2, (const float*)d_in[iL1RE + 1], xu_a, st2, NU, gridU_m,
        meanM, xm_b, ss_m0, wp3, (const float*)d_in[iL1RA + 1], xm_a, st3, NM);
    k_bnfin2<<<2, 128, 0, stream>>>(
        st2, (const float*)d_in[iBN1U], (const float*)d_in[iBN1U + 1], ss_u1, NU,
        st3, (const float*)d_in[iBN1M], (const float*)d_in[iBN1M + 1], ss_m1, NM);

    // ---- classifier ----
    k_cls_mfma<<<(L + 63) / 64, 256, 0, stream>>>(xu_a, ss_u1, xm_a, ss_m1,
        label_src, label_dst, wpc, cls_b1, cls_w2, cls_b2, (float*)d_out, L);
}

// Round 9
// 250.947 us; speedup vs baseline: 1.5895x; 1.1343x over previous
//
#include <hip/hip_runtime.h>
#include <hip/hip_bf16.h>
#include <stdint.h>

#define HD 64
#define CHUNK 4096
#define EPT 16
#define USH 9            // user bucket shift (512-node buckets)
#define MSH 8            // movie bucket shift (256-node buckets)
#define FCAP 12288
#define VMASK 0x7fffffu  // low 23 bits = value; high bits = node-within-bucket
#define NREP 64          // stats replicas (contention spreading)

typedef __bf16 bf16x8 __attribute__((ext_vector_type(8)));
typedef float f32x4 __attribute__((ext_vector_type(4)));
typedef float f32x2 __attribute__((ext_vector_type(2)));

__device__ __forceinline__ void atomAddF(float* p, float v) { unsafeAtomicAdd(p, v); }
__device__ __forceinline__ ushort f2bf(float v) {
    __hip_bfloat16 h = __float2bfloat16(v);
    return *(ushort*)&h;
}
__device__ __forceinline__ uint pack2(float a, float b) {
    return (uint)f2bf(a) | ((uint)f2bf(b) << 16);
}

// ---------------- CSR build (bucket-local) ----------------

__global__ __launch_bounds__(256) void k_bucket_hist(
    const int* __restrict__ src, const int* __restrict__ dst,
    int* __restrict__ bk_u, int* __restrict__ bk_m, int E)
{
    __shared__ int hu[256], hm[256];
    int tid = threadIdx.x;
    hu[tid] = 0; hm[tid] = 0;
    __syncthreads();
    int t = blockIdx.x * 256 + tid;
    int stride = gridDim.x * 256;
    for (; t < E; t += stride) {
        atomicAdd(&hu[src[t] >> USH], 1);
        atomicAdd(&hm[dst[t] >> MSH], 1);
    }
    __syncthreads();
    if (hu[tid]) atomicAdd(&bk_u[tid], hu[tid]);
    if (hm[tid]) atomicAdd(&bk_m[tid], hm[tid]);
}

__global__ void k_bucket_scan(const int* __restrict__ bk_u, const int* __restrict__ bk_m,
                              int* __restrict__ bkrp_u, int* __restrict__ bkrp_m,
                              int* __restrict__ bcur_u, int* __restrict__ bcur_m,
                              int NBu, int NBm, int E)
{
    __shared__ int sh[256];
    int t = threadIdx.x;
    int v = (t < NBu) ? bk_u[t] : 0;
    sh[t] = v; __syncthreads();
    for (int off = 1; off < 256; off <<= 1) {
        int x = (t >= off) ? sh[t - off] : 0;
        __syncthreads(); sh[t] += x; __syncthreads();
    }
    int excl = sh[t] - v;
    if (t < NBu) { bkrp_u[t] = excl; bcur_u[t] = excl; }
    if (t == NBu) bkrp_u[t] = E;
    __syncthreads();
    v = (t < NBm) ? bk_m[t] : 0;
    sh[t] = v; __syncthreads();
    for (int off = 1; off < 256; off <<= 1) {
        int x = (t >= off) ? sh[t - off] : 0;
        __syncthreads(); sh[t] += x; __syncthreads();
    }
    excl = sh[t] - v;
    if (t < NBm) { bkrp_m[t] = excl; bcur_m[t] = excl; }
    if (t == NBm) bkrp_m[t] = E;
}

// one phase of the dual scatter (keys/vals already in registers)
__device__ __forceinline__ void scatter_phase(
    const int* kk, const int* vv, int sh, int NB,
    int* __restrict__ bcur, uint* __restrict__ pairs, int E, int base, int tid,
    int* lcnt, int* lstart, int* gbase, uint2* lpair)
{
    lcnt[tid] = 0;
    __syncthreads();
    int ofs[EPT];
    #pragma unroll
    for (int i = 0; i < EPT; ++i)
        if (kk[i] >= 0) ofs[i] = atomicAdd(&lcnt[kk[i] >> sh], 1);
    __syncthreads();
    int c = lcnt[tid];
    lstart[tid] = c;
    __syncthreads();
    for (int off = 1; off < 256; off <<= 1) {
        int x = (tid >= off) ? lstart[tid - off] : 0;
        __syncthreads(); lstart[tid] += x; __syncthreads();
    }
    lstart[tid] -= c;
    if (c > 0 && tid < NB) gbase[tid] = atomicAdd(&bcur[tid], c);
    __syncthreads();
    #pragma unroll
    for (int i = 0; i < EPT; ++i)
        if (kk[i] >= 0) {
            int b = kk[i] >> sh;
            lpair[lstart[b] + ofs[i]] = make_uint2((uint)kk[i], (uint)vv[i]);
        }
    __syncthreads();
    int total = E - base; if (total > CHUNK) total = CHUNK;
    uint bmask = (1u << sh) - 1u;
    for (int j = tid; j < total; j += 256) {
        uint2 p = lpair[j];
        int b = (int)(p.x >> sh);
        pairs[gbase[b] + (j - lstart[b])] = ((p.x & bmask) << 23) | p.y;
    }
}

// dual-direction scatter: load (src,dst) once, bucket both ways
__global__ __launch_bounds__(256) void k_scatter2(
    const int* __restrict__ srcA, const int* __restrict__ dstA,
    int* __restrict__ bcur_m, uint* __restrict__ pairs_m,
    int* __restrict__ bcur_u, uint* __restrict__ pairs_u,
    int E, int NBm, int NBu)
{
    __shared__ int lcnt[256], lstart[256], gbase[256];
    __shared__ uint2 lpair[CHUNK];
    int tid = threadIdx.x;
    int base = blockIdx.x * CHUNK;
    int ssr[EPT], ddr[EPT];
    #pragma unroll
    for (int i = 0; i < EPT; ++i) {
        int idx = base + i * 256 + tid;
        bool ok = idx < E;
        ssr[i] = ok ? srcA[idx] : -1;
        ddr[i] = ok ? dstA[idx] : -1;
    }
    scatter_phase(ddr, ssr, MSH, NBm, bcur_m, pairs_m, E, base, tid, lcnt, lstart, gbase, lpair);
    __syncthreads();
    scatter_phase(ssr, ddr, USH, NBu, bcur_u, pairs_u, E, base, tid, lcnt, lstart, gbase, lpair);
}

__device__ __forceinline__ void finalize_body(
    const uint* __restrict__ pairs, const int* __restrict__ bkrp,
    int* __restrict__ rp, int* __restrict__ nbr,
    int N, int E, int sh, int b, int NB, int tid,
    int* lcnt, int* lsc, uint* lp)
{
    int base = b << sh;
    int rs = bkrp[b], re = bkrp[b + 1];
    int cnt = re - rs;
    bool staged = cnt <= FCAP;
    lcnt[tid] = 0; lcnt[tid + 256] = 0;
    __syncthreads();
    if (staged) {
        for (int j = tid; j < cnt; j += 256) {
            uint p = pairs[rs + j];
            lp[j] = p;
            atomicAdd(&lcnt[p >> 23], 1);
        }
    } else {
        for (int j = rs + tid; j < re; j += 256)
            atomicAdd(&lcnt[pairs[j] >> 23], 1);
    }
    __syncthreads();
    int c0 = lcnt[2 * tid], c1 = lcnt[2 * tid + 1];
    int s = c0 + c1;
    lsc[tid] = s;
    __syncthreads();
    for (int off = 1; off < 256; off <<= 1) {
        int x = (tid >= off) ? lsc[tid - off] : 0;
        __syncthreads(); lsc[tid] += x; __syncthreads();
    }
    int excl = lsc[tid] - s;
    int nbn = N - base; int bsz = 1 << sh; if (nbn > bsz) nbn = bsz;
    if (2 * tid < nbn)     rp[base + 2 * tid]     = rs + excl;
    if (2 * tid + 1 < nbn) rp[base + 2 * tid + 1] = rs + excl + c0;
    if (b == NB - 1 && tid == 0) rp[N] = E;
    lcnt[2 * tid] = excl;
    lcnt[2 * tid + 1] = excl + c0;
    __syncthreads();
    if (staged) {
        for (int j = tid; j < cnt; j += 256) {
            uint p = lp[j];
            int pos = rs + atomicAdd(&lcnt[p >> 23], 1);
            nbr[pos] = (int)(p & VMASK);
        }
    } else {
        for (int j = rs + tid; j < re; j += 256) {
            uint p = pairs[j];
            int pos = rs + atomicAdd(&lcnt[p >> 23], 1);
            nbr[pos] = (int)(p & VMASK);
        }
    }
}

// combined finalize for both directions: blocks [0,NBm) movie, [NBm, NBm+NBu) user
__global__ __launch_bounds__(256) void k_finalize2(
    const uint* __restrict__ pairs_m, const int* __restrict__ bkrp_m,
    int* __restrict__ rp_m, int* __restrict__ nbr_m, int NM, int NBm,
    const uint* __restrict__ pairs_u, const int* __restrict__ bkrp_u,
    int* __restrict__ rp_u, int* __restrict__ nbr_u, int NU, int NBu, int E)
{
    __shared__ int lcnt[512];
    __shared__ int lsc[256];
    __shared__ uint lp[FCAP];
    int b = blockIdx.x, tid = threadIdx.x;
    if (b < NBm)
        finalize_body(pairs_m, bkrp_m, rp_m, nbr_m, NM, E, MSH, b, NBm, tid, lcnt, lsc, lp);
    else
        finalize_body(pairs_u, bkrp_u, rp_u, nbr_u, NU, E, USH, b - NBm, NBu, tid, lcnt, lsc, lp);
}

// ---------------- weight fragment packing (5 matrices, one kernel) ----------------
__global__ void k_pack_all(const float* __restrict__ w0lo, const float* __restrict__ w0hi,
                           const float* __restrict__ w1lo, const float* __restrict__ w1hi,
                           const float* __restrict__ w2lo, const float* __restrict__ w2hi,
                           const float* __restrict__ w3lo, const float* __restrict__ w3hi,
                           const float* __restrict__ w4lo, const float* __restrict__ w4hi,
                           ushort* __restrict__ dst) {
    int t = blockIdx.x * blockDim.x + threadIdx.x;   // 40960 threads
    int mid = t >> 13, r = t & 8191;
    const float* lo; const float* hi;
    switch (mid) {
        case 0: lo = w0lo; hi = w0hi; break;
        case 1: lo = w1lo; hi = w1hi; break;
        case 2: lo = w2lo; hi = w2hi; break;
        case 3: lo = w3lo; hi = w3hi; break;
        default: lo = w4lo; hi = w4hi;
    }
    int e = r & 7, lane = (r >> 3) & 63, nn = (r >> 9) & 3, kk = r >> 11;
    int k = (lane >> 4) * 8 + e + 32 * kk;
    int col = (lane & 15) + 16 * nn;
    float v = (k < 64) ? lo[k * 64 + col] : hi[(k - 64) * 64 + col];
    dst[t] = f2bf(v);
}

// ---------------- combined init: movie_feat blocks then gather_rows blocks ----------------
__global__ __launch_bounds__(256) void k_init2(
    const float* __restrict__ mx, const float* __restrict__ W,
    const float* __restrict__ b, const float* __restrict__ memb,
    const int* __restrict__ mids, ushort* __restrict__ xm, int NM, int F, int gridMF,
    const float* __restrict__ uemb, const int* __restrict__ uids,
    ushort* __restrict__ xu, int NU)
{
    if ((int)blockIdx.x < gridMF) {
        int m = blockIdx.x * 256 + threadIdx.x;
        if (m >= NM) return;
        const float* xr = mx + (size_t)m * F;
        float acc[HD];
        #pragma unroll
        for (int j = 0; j < HD; ++j) acc[j] = b[j];
        for (int f = 0; f < F; ++f) {
            float v = xr[f];
            #pragma unroll
            for (int j = 0; j < HD; ++j) acc[j] += v * W[f * HD + j];
        }
        int nid = mids[m];
        const float* er = memb + (size_t)nid * HD;
        uint* o = (uint*)(xm + (size_t)m * HD);
        #pragma unroll
        for (int j = 0; j < HD; j += 2)
            o[j >> 1] = pack2(acc[j] + er[j], acc[j + 1] + er[j + 1]);
    } else {
        int t = (blockIdx.x - gridMF) * 256 + threadIdx.x;
        int total = NU * HD;
        int stride = (gridDim.x - gridMF) * 256;
        for (; t < total; t += stride) {
            int i = t >> 6, h = t & 63;
            xu[t] = f2bf(uemb[(size_t)uids[i] * HD + h]);
        }
    }
}

// ---------------- combined segmented mean: 8-lane slots, uint4 rows ----------------
__device__ __forceinline__ void acc_u4(f32x2* acc, uint4 u) {
    uint w[4] = {u.x, u.y, u.z, u.w};
    #pragma unroll
    for (int i = 0; i < 4; ++i)
        acc[i] += (f32x2){__uint_as_float(w[i] << 16), __uint_as_float(w[i] & 0xffff0000u)};
}

__global__ __launch_bounds__(256) void k_reduce2(
    const ushort* __restrict__ xsU, const int* __restrict__ rpU,
    const int* __restrict__ nbrU, ushort* __restrict__ meanU, int NU, int gridU,
    const ushort* __restrict__ xsM, const int* __restrict__ rpM,
    const int* __restrict__ nbrM, ushort* __restrict__ meanM, int NM)
{
    int bid = blockIdx.x;
    const ushort* xsrc; const int* rp; const int* nbr; ushort* mean; int N; int sb;
    if (bid < gridU) { xsrc = xsU; rp = rpU; nbr = nbrU; mean = meanU; N = NU; sb = bid; }
    else             { xsrc = xsM; rp = rpM; nbr = nbrM; mean = meanM; N = NM; sb = bid - gridU; }
    int slot = sb * 32 + (threadIdx.x >> 3);
    if (slot >= N) return;
    uint l = threadIdx.x & 7;
    const uint4* xs = (const uint4*)xsrc;
    int s0 = rp[slot], s1 = rp[slot + 1];
    f32x2 acc[4];
    #pragma unroll
    for (int i = 0; i < 4; ++i) acc[i] = (f32x2){0.f, 0.f};
    int k = s0;
    for (; k + 2 <= s1; k += 2) {
        uint4 u0 = xs[((uint)nbr[k] << 3) + l];
        uint4 u1 = xs[((uint)nbr[k + 1] << 3) + l];
        acc_u4(acc, u0);
        acc_u4(acc, u1);
    }
    if (k < s1) acc_u4(acc, xs[((uint)nbr[k] << 3) + l]);
    float inv = (s1 > s0) ? 1.f / (float)(s1 - s0) : 0.f;
    uint4 o;
    o.x = pack2(acc[0].x * inv, acc[0].y * inv);
    o.y = pack2(acc[1].x * inv, acc[1].y * inv);
    o.z = pack2(acc[2].x * inv, acc[2].y * inv);
    o.w = pack2(acc[3].x * inv, acc[3].y * inv);
    ((uint4*)mean)[((uint)slot << 3) + l] = o;
}

// ---------------- MFMA (no BN — inputs already materialized) ----------------
__device__ __forceinline__ void mfma_body(
    const ushort* __restrict__ meanb, const ushort* __restrict__ xdst,
    const ushort* __restrict__ wp, const float* __restrict__ blv,
    ushort* __restrict__ out, float* __restrict__ stats, int N, int blk, int tid,
    float* lsum, float* lsq)
{
    if (tid < 64) { lsum[tid] = 0.f; lsq[tid] = 0.f; }
    __syncthreads();
    int wave = tid >> 6, lane = tid & 63;
    int n0 = blk * 64 + wave * 16;
    int lrow = lane & 15, lk = lane >> 4;
    int arow = n0 + lrow; if (arow >= N) arow = N - 1;
    const ushort* pm = meanb + (size_t)arow * HD + lk * 8;
    const ushort* px = xdst  + (size_t)arow * HD + lk * 8;
    const bf16x8* wpv = (const bf16x8*)wp + lane;

    bf16x8 b[4][4];
    #pragma unroll
    for (int kk = 0; kk < 4; ++kk)
        #pragma unroll
        for (int nn = 0; nn < 4; ++nn)
            b[kk][nn] = wpv[(kk * 4 + nn) * 64];

    bf16x8 a[4];
    a[0] = *(const bf16x8*)(pm);
    a[1] = *(const bf16x8*)(pm + 32);
    a[2] = *(const bf16x8*)(px);
    a[3] = *(const bf16x8*)(px + 32);

    f32x4 acc[4];
    #pragma unroll
    for (int nn = 0; nn < 4; ++nn) acc[nn] = (f32x4){0.f, 0.f, 0.f, 0.f};
    #pragma unroll
    for (int kk = 0; kk < 4; ++kk)
        #pragma unroll
        for (int nn = 0; nn < 4; ++nn)
            acc[nn] = __builtin_amdgcn_mfma_f32_16x16x32_bf16(a[kk], b[kk][nn], acc[nn], 0, 0, 0);

    #pragma unroll
    for (int nn = 0; nn < 4; ++nn) {
        float bias = blv[lrow + 16 * nn];
        float s = 0.f, q = 0.f;
        #pragma unroll
        for (int r = 0; r < 4; ++r) {
            int orow = n0 + lk * 4 + r;
            float v = acc[nn][r] + bias;
            bool ok = orow < N;
            if (ok) out[(size_t)orow * HD + lrow + 16 * nn] = f2bf(v);
            float vv = ok ? v : 0.f;
            s += vv; q += vv * vv;
        }
        s += __shfl_xor(s, 16); s += __shfl_xor(s, 32);
        q += __shfl_xor(q, 16); q += __shfl_xor(q, 32);
        if (lk == 0) {
            atomAddF(&lsum[lrow + 16 * nn], s);
            atomAddF(&lsq[lrow + 16 * nn], q);
        }
    }
    __syncthreads();
    float* st = stats + (size_t)(blk & (NREP - 1)) * 128;
    if (tid < 64) {
        atomAddF(&st[tid], lsum[tid]);
        atomAddF(&st[64 + tid], lsq[tid]);
    }
}

__global__ __launch_bounds__(256) void k_mfma2(
    const ushort* __restrict__ meanU, const ushort* __restrict__ xuD,
    const ushort* __restrict__ wpU, const float* __restrict__ blU,
    ushort* __restrict__ outU, float* __restrict__ stU, int NU, int gridU,
    const ushort* __restrict__ meanM, const ushort* __restrict__ xmD,
    const ushort* __restrict__ wpM, const float* __restrict__ blM,
    ushort* __restrict__ outM, float* __restrict__ stM, int NM)
{
    __shared__ float lsum[64], lsq[64];
    int bid = blockIdx.x, tid = threadIdx.x;
    if (bid < gridU)
        mfma_body(meanU, xuD, wpU, blU, outU, stU, NU, bid, tid, lsum, lsq);
    else
        mfma_body(meanM, xmD, wpM, blM, outM, stM, NM, bid - gridU, tid, lsum, lsq);
}

// combined BN finalize: block 0 = user, block 1 = movie
__global__ void k_bnfin2(const float* __restrict__ stA, const float* __restrict__ gA,
                         const float* __restrict__ bA, float* __restrict__ ssA, int NA,
                         const float* __restrict__ stB, const float* __restrict__ gB,
                         const float* __restrict__ bB, float* __restrict__ ssB, int NB_)
{
    __shared__ float red[128];
    const float* stats; const float* g; const float* b; float* ss; int N;
    if (blockIdx.x == 0) { stats = stA; g = gA; b = bA; ss = ssA; N = NA; }
    else                 { stats = stB; g = gB; b = bB; ss = ssB; N = NB_; }
    int j = threadIdx.x;   // 0..127
    float s = 0.f;
    #pragma unroll 8
    for (int r = 0; r < NREP; ++r) s += stats[r * 128 + j];
    red[j] = s;
    __syncthreads();
    if (j < HD) {
        float invN = 1.f / (float)N;
        float mu = red[j] * invN;
        float var = red[HD + j] * invN - mu * mu;
        var = var < 0.f ? 0.f : var;
        float sc = g[j] * rsqrtf(var + 1e-5f);
        ss[j] = sc;
        ss[HD + j] = b[j] - mu * sc;
    }
}

// apply BN+ReLU in place to both per-type buffers (uint4 granularity; 8 cols per uint4)
__global__ __launch_bounds__(256) void k_bnapply2(
    uint4* __restrict__ xa, const float* __restrict__ ssa, int qa,
    uint4* __restrict__ xb, const float* __restrict__ ssb, int qb)
{
    int t = blockIdx.x * 256 + threadIdx.x;
    int stride = gridDim.x * 256;
    int total = qa + qb;
    for (; t < total; t += stride) {
        uint4* x; const float* ss; int i;
        if (t < qa) { x = xa; ss = ssa; i = t; }
        else        { x = xb; ss = ssb; i = t - qa; }
        int cb = (i & 7) * 8;
        uint4 u = x[i];
        uint w[4] = {u.x, u.y, u.z, u.w};
        #pragma unroll
        for (int j = 0; j < 4; ++j) {
            float f0 = __uint_as_float(w[j] << 16)         * ss[cb + 2 * j]     + ss[64 + cb + 2 * j];
            float f1 = __uint_as_float(w[j] & 0xffff0000u) * ss[cb + 2 * j + 1] + ss[64 + cb + 2 * j + 1];
            w[j] = pack2(fmaxf(f0, 0.f), fmaxf(f1, 0.f));
        }
        x[i] = make_uint4(w[0], w[1], w[2], w[3]);
    }
}

// ---------------- classifier (inputs already BN'd) ----------------
__global__ __launch_bounds__(256) void k_cls_mfma(
    const ushort* __restrict__ xu, const ushort* __restrict__ xm,
    const int* __restrict__ lsrc, const int* __restrict__ ldst,
    const ushort* __restrict__ wp, const float* __restrict__ b1,
    const float* __restrict__ w2, const float* __restrict__ b2,
    float* __restrict__ out, int L)
{
    int wave = threadIdx.x >> 6, lane = threadIdx.x & 63;
    int l0 = blockIdx.x * 64 + wave * 16;
    if (l0 >= L) return;
    int lrow = lane & 15, lk = lane >> 4;
    int li = l0 + lrow; if (li >= L) li = L - 1;
    const ushort* pu = xu + (size_t)lsrc[li] * HD + lk * 8;
    const ushort* pm = xm + (size_t)ldst[li] * HD + lk * 8;
    const bf16x8* wpv = (const bf16x8*)wp + lane;

    bf16x8 a[4];
    a[0] = *(const bf16x8*)(pu);
    a[1] = *(const bf16x8*)(pu + 32);
    a[2] = *(const bf16x8*)(pm);
    a[3] = *(const bf16x8*)(pm + 32);

    f32x4 acc[4];
    #pragma unroll
    for (int nn = 0; nn < 4; ++nn) acc[nn] = (f32x4){0.f, 0.f, 0.f, 0.f};
    #pragma unroll
    for (int kk = 0; kk < 4; ++kk)
        #pragma unroll
        for (int nn = 0; nn < 4; ++nn)
            acc[nn] = __builtin_amdgcn_mfma_f32_16x16x32_bf16(a[kk], wpv[(kk * 4 + nn) * 64], acc[nn], 0, 0, 0);

    float p0 = 0.f, p1 = 0.f, p2 = 0.f, p3 = 0.f;
    #pragma unroll
    for (int nn = 0; nn < 4; ++nn) {
        int cidx = lrow + 16 * nn;
        float bb = b1[cidx], w = w2[cidx];
        p0 += fmaxf(acc[nn][0] + bb, 0.f) * w;
        p1 += fmaxf(acc[nn][1] + bb, 0.f) * w;
        p2 += fmaxf(acc[nn][2] + bb, 0.f) * w;
        p3 += fmaxf(acc[nn][3] + bb, 0.f) * w;
    }
    #pragma unroll
    for (int off = 1; off < 16; off <<= 1) {
        p0 += __shfl_xor(p0, off);
        p1 += __shfl_xor(p1, off);
        p2 += __shfl_xor(p2, off);
        p3 += __shfl_xor(p3, off);
    }
    if (lrow == 0) {
        float bb2 = b2[0];
        int r0 = l0 + lk * 4;
        if (r0 + 0 < L) out[r0 + 0] = p0 + bb2;
        if (r0 + 1 < L) out[r0 + 1] = p1 + bb2;
        if (r0 + 2 < L) out[r0 + 2] = p2 + bb2;
        if (r0 + 3 < L) out[r0 + 3] = p3 + bb2;
    }
}

extern "C" void kernel_launch(void* const* d_in, const int* in_sizes, int n_in,
                              void* d_out, int out_size, void* d_ws, size_t ws_size,
                              hipStream_t stream) {
    (void)n_in; (void)ws_size;
    const int NU = in_sizes[1] / HD;
    const int NM = in_sizes[2] / HD;
    const int F  = in_sizes[0] / NM;
    const int E  = in_sizes[31];
    const int L  = out_size;
    const int NBm = (NM + (1 << MSH) - 1) >> MSH;
    const int NBu = (NU + (1 << USH) - 1) >> USH;

    int iL0RA, iL0RE, iL1RA, iL1RE, iBN0U, iBN0M, iBN1U, iBN1M;
    if (in_sizes[11] == HD) {          // setup-dict order
        iL0RA = 5; iL0RE = 8; iBN0U = 11; iBN0M = 13;
        iL1RA = 15; iL1RE = 18; iBN1U = 21; iBN1M = 23;
    } else {                           // reference-signature order
        iL0RA = 5; iL0RE = 8; iL1RA = 11; iL1RE = 14;
        iBN0U = 17; iBN0M = 19; iBN1U = 21; iBN1M = 23;
    }
    const float* movie_x   = (const float*)d_in[0];
    const float* user_emb  = (const float*)d_in[1];
    const float* movie_emb = (const float*)d_in[2];
    const float* mlw       = (const float*)d_in[3];
    const float* mlb       = (const float*)d_in[4];
    const float* cls_w1    = (const float*)d_in[25];
    const float* cls_b1    = (const float*)d_in[26];
    const float* cls_w2    = (const float*)d_in[27];
    const float* cls_b2    = (const float*)d_in[28];
    const int* user_node_id  = (const int*)d_in[29];
    const int* movie_node_id = (const int*)d_in[30];
    const int* rates_src   = (const int*)d_in[31];
    const int* rates_dst   = (const int*)d_in[32];
    const int* label_src   = (const int*)d_in[33];
    const int* label_dst   = (const int*)d_in[34];

    // ---- workspace ----
    char* wsb = (char*)d_ws;
    auto alloc = [&](size_t bytes) { char* p = wsb; wsb += (bytes + 255) & ~(size_t)255; return p; };
    ushort* xu_a = (ushort*)alloc((size_t)NU * HD * 2);
    ushort* xu_b = (ushort*)alloc((size_t)NU * HD * 2);
    ushort* xm_a = (ushort*)alloc((size_t)NM * HD * 2);
    ushort* xm_b = (ushort*)alloc((size_t)NM * HD * 2);
    ushort* meanU = (ushort*)alloc((size_t)NU * HD * 2);
    ushort* meanM = (ushort*)alloc((size_t)NM * HD * 2);
    ushort* wp_all = (ushort*)alloc(5 * 8192 * 2);
    int* rp_m = (int*)alloc((size_t)(NM + 1) * 4);
    int* rp_u = (int*)alloc((size_t)(NU + 1) * 4);
    int* nbr_m = (int*)alloc((size_t)E * 4);
    int* nbr_u = (int*)alloc((size_t)E * 4);
    uint* pairs_m = (uint*)alloc((size_t)E * 4);
    uint* pairs_u = (uint*)alloc((size_t)E * 4);
    int* bkrp_m = (int*)alloc(257 * 4);
    int* bkrp_u = (int*)alloc(257 * 4);
    int* bcur_m = (int*)alloc(256 * 4);
    int* bcur_u = (int*)alloc(256 * 4);
    size_t zr_bytes = 2 * 256 * 4 + (size_t)4 * NREP * 128 * 4;
    char* zr = alloc(zr_bytes);
    int* bk_u = (int*)zr;
    int* bk_m = bk_u + 256;
    float* statsAll = (float*)(bk_m + 256);
    float* ss_u0 = (float*)alloc(128 * 4);
    float* ss_m0 = (float*)alloc(128 * 4);
    float* ss_u1 = (float*)alloc(128 * 4);
    float* ss_m1 = (float*)alloc(128 * 4);

    ushort* wp0 = wp_all;              // l0 rev (user stage)
    ushort* wp1 = wp_all + 8192;       // l0 rates (movie stage)
    ushort* wp2 = wp_all + 16384;      // l1 rev
    ushort* wp3 = wp_all + 24576;      // l1 rates
    ushort* wpc = wp_all + 32768;      // classifier
    float* st0 = statsAll;
    float* st1 = statsAll + NREP * 128;
    float* st2 = statsAll + 2 * NREP * 128;
    float* st3 = statsAll + 3 * NREP * 128;

    const int sgrid = (E + CHUNK - 1) / CHUNK;
    const int gridU_r = (NU + 31) / 32, gridM_r = (NM + 31) / 32;
    const int gridU_m = (NU + 63) / 64, gridM_m = (NM + 63) / 64;
    const int gridMF = (NM + 255) / 256;
    const int qU = NU * 8, qM = NM * 8;                  // uint4 counts
    const int gridBA = (qU + qM + 255) / 256;

    hipMemsetAsync(zr, 0, zr_bytes, stream);
    k_pack_all<<<160, 256, 0, stream>>>(
        (const float*)d_in[iL0RE + 0], (const float*)d_in[iL0RE + 2],
        (const float*)d_in[iL0RA + 0], (const float*)d_in[iL0RA + 2],
        (const float*)d_in[iL1RE + 0], (const float*)d_in[iL1RE + 2],
        (const float*)d_in[iL1RA + 0], (const float*)d_in[iL1RA + 2],
        cls_w1, cls_w1 + 64 * 64, wp_all);

    // ---- CSR build (dual-direction, bucket-local) ----
    k_bucket_hist<<<1024, 256, 0, stream>>>(rates_src, rates_dst, bk_u, bk_m, E);
    k_bucket_scan<<<1, 256, 0, stream>>>(bk_u, bk_m, bkrp_u, bkrp_m, bcur_u, bcur_m, NBu, NBm, E);
    k_scatter2<<<sgrid, 256, 0, stream>>>(rates_src, rates_dst, bcur_m, pairs_m, bcur_u, pairs_u, E, NBm, NBu);
    k_finalize2<<<NBm + NBu, 256, 0, stream>>>(pairs_m, bkrp_m, rp_m, nbr_m, NM, NBm,
                                               pairs_u, bkrp_u, rp_u, nbr_u, NU, NBu, E);

    // ---- init node features ----
    k_init2<<<gridMF + 2048, 256, 0, stream>>>(movie_x, mlw, mlb, movie_emb, movie_node_id,
                                               xm_a, NM, F, gridMF, user_emb, user_node_id, xu_a, NU);

    // ---- layer 0 ----
    k_reduce2<<<gridU_r + gridM_r, 256, 0, stream>>>(
        xm_a, rp_u, nbr_u, meanU, NU, gridU_r,
        xu_a, rp_m, nbr_m, meanM, NM);
    k_mfma2<<<gridU_m + gridM_m, 256, 0, stream>>>(
        meanU, xu_a, wp0, (const float*)d_in[iL0RE + 1], xu_b, st0, NU, gridU_m,
        meanM, xm_a, wp1, (const float*)d_in[iL0RA + 1], xm_b, st1, NM);
    k_bnfin2<<<2, 128, 0, stream>>>(
        st0, (const float*)d_in[iBN0U], (const float*)d_in[iBN0U + 1], ss_u0, NU,
        st1, (const float*)d_in[iBN0M], (const float*)d_in[iBN0M + 1], ss_m0, NM);
    k_bnapply2<<<gridBA, 256, 0, stream>>>((uint4*)xu_b, ss_u0, qU, (uint4*)xm_b, ss_m0, qM);

    // ---- layer 1 ----
    k_reduce2<<<gridU_r + gridM_r, 256, 0, stream>>>(
        xm_b, rp_u, nbr_u, meanU, NU, gridU_r,
        xu_b, rp_m, nbr_m, meanM, NM);
    k_mfma2<<<gridU_m + gridM_m, 256, 0, stream>>>(
        meanU, xu_b, wp2, (const float*)d_in[iL1RE + 1], xu_a, st2, NU, gridU_m,
        meanM, xm_b, wp3, (const float*)d_in[iL1RA + 1], xm_a, st3, NM);
    k_bnfin2<<<2, 128, 0, stream>>>(
        st2, (const float*)d_in[iBN1U], (const float*)d_in[iBN1U + 1], ss_u1, NU,
        st3, (const float*)d_in[iBN1M], (const float*)d_in[iBN1M + 1], ss_m1, NM);
    k_bnapply2<<<gridBA, 256, 0, stream>>>((uint4*)xu_a, ss_u1, qU, (uint4*)xm_a, ss_m1, qM);

    // ---- classifier ----
    k_cls_mfma<<<(L + 63) / 64, 256, 0, stream>>>(xu_a, xm_a,
        label_src, label_dst, wpc, cls_b1, cls_w2, cls_b2, (float*)d_out, L);
}

// Round 11
// 244.898 us; speedup vs baseline: 1.6287x; 1.0247x over previous
//
#include <hip/hip_runtime.h>
#include <hip/hip_bf16.h>
#include <stdint.h>

#define HD 64
#define CHUNK 4096
#define EPT 16
#define USH 9            // user bucket shift (512-node buckets)
#define MSH 8            // movie bucket shift (256-node buckets)
#define FCAP 12288
#define VMASK 0x7fffffu  // low 23 bits = value; high bits = node-within-bucket
#define NREP 64          // stats replicas (contention spreading)

typedef __bf16 bf16x8 __attribute__((ext_vector_type(8)));
typedef float f32x4 __attribute__((ext_vector_type(4)));
typedef float f32x2 __attribute__((ext_vector_type(2)));

__device__ __forceinline__ void atomAddF(float* p, float v) { unsafeAtomicAdd(p, v); }
__device__ __forceinline__ ushort f2bf(float v) {
    __hip_bfloat16 h = __float2bfloat16(v);
    return *(ushort*)&h;
}
__device__ __forceinline__ uint pack2(float a, float b) {
    return (uint)f2bf(a) | ((uint)f2bf(b) << 16);
}

// ---------------- CSR build (bucket-local) ----------------

__global__ __launch_bounds__(256) void k_bucket_hist(
    const int* __restrict__ src, const int* __restrict__ dst,
    int* __restrict__ bk_u, int* __restrict__ bk_m, int E)
{
    __shared__ int hu[256], hm[256];
    int tid = threadIdx.x;
    hu[tid] = 0; hm[tid] = 0;
    __syncthreads();
    int t = blockIdx.x * 256 + tid;
    int stride = gridDim.x * 256;
    for (; t < E; t += stride) {
        atomicAdd(&hu[src[t] >> USH], 1);
        atomicAdd(&hm[dst[t] >> MSH], 1);
    }
    __syncthreads();
    if (hu[tid]) atomicAdd(&bk_u[tid], hu[tid]);
    if (hm[tid]) atomicAdd(&bk_m[tid], hm[tid]);
}

__global__ void k_bucket_scan(const int* __restrict__ bk_u, const int* __restrict__ bk_m,
                              int* __restrict__ bkrp_u, int* __restrict__ bkrp_m,
                              int* __restrict__ bcur_u, int* __restrict__ bcur_m,
                              int NBu, int NBm, int E)
{
    __shared__ int sh[256];
    int t = threadIdx.x;
    int v = (t < NBu) ? bk_u[t] : 0;
    sh[t] = v; __syncthreads();
    for (int off = 1; off < 256; off <<= 1) {
        int x = (t >= off) ? sh[t - off] : 0;
        __syncthreads(); sh[t] += x; __syncthreads();
    }
    int excl = sh[t] - v;
    if (t < NBu) { bkrp_u[t] = excl; bcur_u[t] = excl; }
    if (t == NBu) bkrp_u[t] = E;
    __syncthreads();
    v = (t < NBm) ? bk_m[t] : 0;
    sh[t] = v; __syncthreads();
    for (int off = 1; off < 256; off <<= 1) {
        int x = (t >= off) ? sh[t - off] : 0;
        __syncthreads(); sh[t] += x; __syncthreads();
    }
    excl = sh[t] - v;
    if (t < NBm) { bkrp_m[t] = excl; bcur_m[t] = excl; }
    if (t == NBm) bkrp_m[t] = E;
}

// one phase of the dual scatter (keys/vals already in registers)
__device__ __forceinline__ void scatter_phase(
    const int* kk, const int* vv, int sh, int NB,
    int* __restrict__ bcur, uint* __restrict__ pairs, int E, int base, int tid,
    int* lcnt, int* lstart, int* gbase, uint2* lpair)
{
    lcnt[tid] = 0;
    __syncthreads();
    int ofs[EPT];
    #pragma unroll
    for (int i = 0; i < EPT; ++i)
        if (kk[i] >= 0) ofs[i] = atomicAdd(&lcnt[kk[i] >> sh], 1);
    __syncthreads();
    int c = lcnt[tid];
    lstart[tid] = c;
    __syncthreads();
    for (int off = 1; off < 256; off <<= 1) {
        int x = (tid >= off) ? lstart[tid - off] : 0;
        __syncthreads(); lstart[tid] += x; __syncthreads();
    }
    lstart[tid] -= c;
    if (c > 0 && tid < NB) gbase[tid] = atomicAdd(&bcur[tid], c);
    __syncthreads();
    #pragma unroll
    for (int i = 0; i < EPT; ++i)
        if (kk[i] >= 0) {
            int b = kk[i] >> sh;
            lpair[lstart[b] + ofs[i]] = make_uint2((uint)kk[i], (uint)vv[i]);
        }
    __syncthreads();
    int total = E - base; if (total > CHUNK) total = CHUNK;
    uint bmask = (1u << sh) - 1u;
    for (int j = tid; j < total; j += 256) {
        uint2 p = lpair[j];
        int b = (int)(p.x >> sh);
        pairs[gbase[b] + (j - lstart[b])] = ((p.x & bmask) << 23) | p.y;
    }
}

// dual-direction scatter: load (src,dst) once, bucket both ways
__global__ __launch_bounds__(256) void k_scatter2(
    const int* __restrict__ srcA, const int* __restrict__ dstA,
    int* __restrict__ bcur_m, uint* __restrict__ pairs_m,
    int* __restrict__ bcur_u, uint* __restrict__ pairs_u,
    int E, int NBm, int NBu)
{
    __shared__ int lcnt[256], lstart[256], gbase[256];
    __shared__ uint2 lpair[CHUNK];
    int tid = threadIdx.x;
    int base = blockIdx.x * CHUNK;
    int ssr[EPT], ddr[EPT];
    #pragma unroll
    for (int i = 0; i < EPT; ++i) {
        int idx = base + i * 256 + tid;
        bool ok = idx < E;
        ssr[i] = ok ? srcA[idx] : -1;
        ddr[i] = ok ? dstA[idx] : -1;
    }
    scatter_phase(ddr, ssr, MSH, NBm, bcur_m, pairs_m, E, base, tid, lcnt, lstart, gbase, lpair);
    __syncthreads();
    scatter_phase(ssr, ddr, USH, NBu, bcur_u, pairs_u, E, base, tid, lcnt, lstart, gbase, lpair);
}

__device__ __forceinline__ void finalize_body(
    const uint* __restrict__ pairs, const int* __restrict__ bkrp,
    int* __restrict__ rp, int* __restrict__ nbr,
    int N, int E, int sh, int b, int NB, int tid,
    int* lcnt, int* lsc, uint* lp)
{
    int base = b << sh;
    int rs = bkrp[b], re = bkrp[b + 1];
    int cnt = re - rs;
    bool staged = cnt <= FCAP;
    lcnt[tid] = 0; lcnt[tid + 256] = 0;
    __syncthreads();
    if (staged) {
        for (int j = tid; j < cnt; j += 256) {
            uint p = pairs[rs + j];
            lp[j] = p;
            atomicAdd(&lcnt[p >> 23], 1);
        }
    } else {
        for (int j = rs + tid; j < re; j += 256)
            atomicAdd(&lcnt[pairs[j] >> 23], 1);
    }
    __syncthreads();
    int c0 = lcnt[2 * tid], c1 = lcnt[2 * tid + 1];
    int s = c0 + c1;
    lsc[tid] = s;
    __syncthreads();
    for (int off = 1; off < 256; off <<= 1) {
        int x = (tid >= off) ? lsc[tid - off] : 0;
        __syncthreads(); lsc[tid] += x; __syncthreads();
    }
    int excl = lsc[tid] - s;
    int nbn = N - base; int bsz = 1 << sh; if (nbn > bsz) nbn = bsz;
    if (2 * tid < nbn)     rp[base + 2 * tid]     = rs + excl;
    if (2 * tid + 1 < nbn) rp[base + 2 * tid + 1] = rs + excl + c0;
    if (b == NB - 1 && tid == 0) rp[N] = E;
    lcnt[2 * tid] = excl;
    lcnt[2 * tid + 1] = excl + c0;
    __syncthreads();
    if (staged) {
        for (int j = tid; j < cnt; j += 256) {
            uint p = lp[j];
            int pos = rs + atomicAdd(&lcnt[p >> 23], 1);
            nbr[pos] = (int)(p & VMASK);
        }
    } else {
        for (int j = rs + tid; j < re; j += 256) {
            uint p = pairs[j];
            int pos = rs + atomicAdd(&lcnt[p >> 23], 1);
            nbr[pos] = (int)(p & VMASK);
        }
    }
}

// combined finalize for both directions: blocks [0,NBm) movie, [NBm, NBm+NBu) user
__global__ __launch_bounds__(256) void k_finalize2(
    const uint* __restrict__ pairs_m, const int* __restrict__ bkrp_m,
    int* __restrict__ rp_m, int* __restrict__ nbr_m, int NM, int NBm,
    const uint* __restrict__ pairs_u, const int* __restrict__ bkrp_u,
    int* __restrict__ rp_u, int* __restrict__ nbr_u, int NU, int NBu, int E)
{
    __shared__ int lcnt[512];
    __shared__ int lsc[256];
    __shared__ uint lp[FCAP];
    int b = blockIdx.x, tid = threadIdx.x;
    if (b < NBm)
        finalize_body(pairs_m, bkrp_m, rp_m, nbr_m, NM, E, MSH, b, NBm, tid, lcnt, lsc, lp);
    else
        finalize_body(pairs_u, bkrp_u, rp_u, nbr_u, NU, E, USH, b - NBm, NBu, tid, lcnt, lsc, lp);
}

// ---------------- weight fragment packing (5 matrices, one kernel) ----------------
__global__ void k_pack_all(const float* __restrict__ w0lo, const float* __restrict__ w0hi,
                           const float* __restrict__ w1lo, const float* __restrict__ w1hi,
                           const float* __restrict__ w2lo, const float* __restrict__ w2hi,
                           const float* __restrict__ w3lo, const float* __restrict__ w3hi,
                           const float* __restrict__ w4lo, const float* __restrict__ w4hi,
                           ushort* __restrict__ dst) {
    int t = blockIdx.x * blockDim.x + threadIdx.x;   // 40960 threads
    int mid = t >> 13, r = t & 8191;
    const float* lo; const float* hi;
    switch (mid) {
        case 0: lo = w0lo; hi = w0hi; break;
        case 1: lo = w1lo; hi = w1hi; break;
        case 2: lo = w2lo; hi = w2hi; break;
        case 3: lo = w3lo; hi = w3hi; break;
        default: lo = w4lo; hi = w4hi;
    }
    int e = r & 7, lane = (r >> 3) & 63, nn = (r >> 9) & 3, kk = r >> 11;
    int k = (lane >> 4) * 8 + e + 32 * kk;
    int col = (lane & 15) + 16 * nn;
    float v = (k < 64) ? lo[k * 64 + col] : hi[(k - 64) * 64 + col];
    dst[t] = f2bf(v);
}

// ---------------- combined init: movie_feat blocks then gather_rows blocks ----------------
__global__ __launch_bounds__(256) void k_init2(
    const float* __restrict__ mx, const float* __restrict__ W,
    const float* __restrict__ b, const float* __restrict__ memb,
    const int* __restrict__ mids, ushort* __restrict__ xm, int NM, int F, int gridMF,
    const float* __restrict__ uemb, const int* __restrict__ uids,
    ushort* __restrict__ xu, int NU)
{
    if ((int)blockIdx.x < gridMF) {
        int m = blockIdx.x * 256 + threadIdx.x;
        if (m >= NM) return;
        const float* xr = mx + (size_t)m * F;
        float acc[HD];
        #pragma unroll
        for (int j = 0; j < HD; ++j) acc[j] = b[j];
        for (int f = 0; f < F; ++f) {
            float v = xr[f];
            #pragma unroll
            for (int j = 0; j < HD; ++j) acc[j] += v * W[f * HD + j];
        }
        int nid = mids[m];
        const float* er = memb + (size_t)nid * HD;
        uint* o = (uint*)(xm + (size_t)m * HD);
        #pragma unroll
        for (int j = 0; j < HD; j += 2)
            o[j >> 1] = pack2(acc[j] + er[j], acc[j + 1] + er[j + 1]);
    } else {
        int t = (blockIdx.x - gridMF) * 256 + threadIdx.x;
        int total = NU * HD;
        int stride = (gridDim.x - gridMF) * 256;
        for (; t < total; t += stride) {
            int i = t >> 6, h = t & 63;
            xu[t] = f2bf(uemb[(size_t)uids[i] * HD + h]);
        }
    }
}

// ---------------- combined segmented mean: 8-lane slots, uint4 rows, unroll 4 ----------------
__device__ __forceinline__ void acc_u4(f32x2* acc, uint4 u) {
    uint w[4] = {u.x, u.y, u.z, u.w};
    #pragma unroll
    for (int i = 0; i < 4; ++i)
        acc[i] += (f32x2){__uint_as_float(w[i] << 16), __uint_as_float(w[i] & 0xffff0000u)};
}

__global__ __launch_bounds__(256) void k_reduce2(
    const ushort* __restrict__ xsU, const int* __restrict__ rpU,
    const int* __restrict__ nbrU, ushort* __restrict__ meanU, int NU, int gridU,
    const ushort* __restrict__ xsM, const int* __restrict__ rpM,
    const int* __restrict__ nbrM, ushort* __restrict__ meanM, int NM)
{
    int bid = blockIdx.x;
    const ushort* xsrc; const int* rp; const int* nbr; ushort* mean; int N; int sb;
    if (bid < gridU) { xsrc = xsU; rp = rpU; nbr = nbrU; mean = meanU; N = NU; sb = bid; }
    else             { xsrc = xsM; rp = rpM; nbr = nbrM; mean = meanM; N = NM; sb = bid - gridU; }
    int slot = sb * 32 + (threadIdx.x >> 3);
    if (slot >= N) return;
    uint l = threadIdx.x & 7;
    const uint4* xs = (const uint4*)xsrc;
    int s0 = rp[slot], s1 = rp[slot + 1];
    f32x2 acc[4];
    #pragma unroll
    for (int i = 0; i < 4; ++i) acc[i] = (f32x2){0.f, 0.f};
    int k = s0;
    for (; k + 4 <= s1; k += 4) {
        uint n0 = (uint)nbr[k], n1 = (uint)nbr[k + 1];
        uint n2 = (uint)nbr[k + 2], n3 = (uint)nbr[k + 3];
        uint4 u0 = xs[(n0 << 3) + l];
        uint4 u1 = xs[(n1 << 3) + l];
        uint4 u2 = xs[(n2 << 3) + l];
        uint4 u3 = xs[(n3 << 3) + l];
        acc_u4(acc, u0);
        acc_u4(acc, u1);
        acc_u4(acc, u2);
        acc_u4(acc, u3);
    }
    for (; k < s1; ++k) acc_u4(acc, xs[((uint)nbr[k] << 3) + l]);
    float inv = (s1 > s0) ? 1.f / (float)(s1 - s0) : 0.f;
    uint4 o;
    o.x = pack2(acc[0].x * inv, acc[0].y * inv);
    o.y = pack2(acc[1].x * inv, acc[1].y * inv);
    o.z = pack2(acc[2].x * inv, acc[2].y * inv);
    o.w = pack2(acc[3].x * inv, acc[3].y * inv);
    ((uint4*)mean)[((uint)slot << 3) + l] = o;
}

// ---------------- MFMA (no BN — inputs already materialized) ----------------
__device__ __forceinline__ void mfma_body(
    const ushort* __restrict__ meanb, const ushort* __restrict__ xdst,
    const ushort* __restrict__ wp, const float* __restrict__ blv,
    ushort* __restrict__ out, float* __restrict__ stats, int N, int blk, int tid,
    float* lsum, float* lsq)
{
    if (tid < 64) { lsum[tid] = 0.f; lsq[tid] = 0.f; }
    __syncthreads();
    int wave = tid >> 6, lane = tid & 63;
    int n0 = blk * 64 + wave * 16;
    int lrow = lane & 15, lk = lane >> 4;
    int arow = n0 + lrow; if (arow >= N) arow = N - 1;
    const ushort* pm = meanb + (size_t)arow * HD + lk * 8;
    const ushort* px = xdst  + (size_t)arow * HD + lk * 8;
    const bf16x8* wpv = (const bf16x8*)wp + lane;

    bf16x8 b[4][4];
    #pragma unroll
    for (int kk = 0; kk < 4; ++kk)
        #pragma unroll
        for (int nn = 0; nn < 4; ++nn)
            b[kk][nn] = wpv[(kk * 4 + nn) * 64];

    bf16x8 a[4];
    a[0] = *(const bf16x8*)(pm);
    a[1] = *(const bf16x8*)(pm + 32);
    a[2] = *(const bf16x8*)(px);
    a[3] = *(const bf16x8*)(px + 32);

    f32x4 acc[4];
    #pragma unroll
    for (int nn = 0; nn < 4; ++nn) acc[nn] = (f32x4){0.f, 0.f, 0.f, 0.f};
    #pragma unroll
    for (int kk = 0; kk < 4; ++kk)
        #pragma unroll
        for (int nn = 0; nn < 4; ++nn)
            acc[nn] = __builtin_amdgcn_mfma_f32_16x16x32_bf16(a[kk], b[kk][nn], acc[nn], 0, 0, 0);

    #pragma unroll
    for (int nn = 0; nn < 4; ++nn) {
        float bias = blv[lrow + 16 * nn];
        float s = 0.f, q = 0.f;
        #pragma unroll
        for (int r = 0; r < 4; ++r) {
            int orow = n0 + lk * 4 + r;
            float v = acc[nn][r] + bias;
            bool ok = orow < N;
            if (ok) out[(size_t)orow * HD + lrow + 16 * nn] = f2bf(v);
            float vv = ok ? v : 0.f;
            s += vv; q += vv * vv;
        }
        s += __shfl_xor(s, 16); s += __shfl_xor(s, 32);
        q += __shfl_xor(q, 16); q += __shfl_xor(q, 32);
        if (lk == 0) {
            atomAddF(&lsum[lrow + 16 * nn], s);
            atomAddF(&lsq[lrow + 16 * nn], q);
        }
    }
    __syncthreads();
    float* st = stats + (size_t)(blk & (NREP - 1)) * 128;
    if (tid < 64) {
        atomAddF(&st[tid], lsum[tid]);
        atomAddF(&st[64 + tid], lsq[tid]);
    }
}

__global__ __launch_bounds__(256) void k_mfma2(
    const ushort* __restrict__ meanU, const ushort* __restrict__ xuD,
    const ushort* __restrict__ wpU, const float* __restrict__ blU,
    ushort* __restrict__ outU, float* __restrict__ stU, int NU, int gridU,
    const ushort* __restrict__ meanM, const ushort* __restrict__ xmD,
    const ushort* __restrict__ wpM, const float* __restrict__ blM,
    ushort* __restrict__ outM, float* __restrict__ stM, int NM)
{
    __shared__ float lsum[64], lsq[64];
    int bid = blockIdx.x, tid = threadIdx.x;
    if (bid < gridU)
        mfma_body(meanU, xuD, wpU, blU, outU, stU, NU, bid, tid, lsum, lsq);
    else
        mfma_body(meanM, xmD, wpM, blM, outM, stM, NM, bid - gridU, tid, lsum, lsq);
}

// combined BN finalize: block 0 = user, block 1 = movie
__global__ void k_bnfin2(const float* __restrict__ stA, const float* __restrict__ gA,
                         const float* __restrict__ bA, float* __restrict__ ssA, int NA,
                         const float* __restrict__ stB, const float* __restrict__ gB,
                         const float* __restrict__ bB, float* __restrict__ ssB, int NB_)
{
    __shared__ float red[128];
    const float* stats; const float* g; const float* b; float* ss; int N;
    if (blockIdx.x == 0) { stats = stA; g = gA; b = bA; ss = ssA; N = NA; }
    else                 { stats = stB; g = gB; b = bB; ss = ssB; N = NB_; }
    int j = threadIdx.x;   // 0..127
    float s = 0.f;
    #pragma unroll 8
    for (int r = 0; r < NREP; ++r) s += stats[r * 128 + j];
    red[j] = s;
    __syncthreads();
    if (j < HD) {
        float invN = 1.f / (float)N;
        float mu = red[j] * invN;
        float var = red[HD + j] * invN - mu * mu;
        var = var < 0.f ? 0.f : var;
        float sc = g[j] * rsqrtf(var + 1e-5f);
        ss[j] = sc;
        ss[HD + j] = b[j] - mu * sc;
    }
}

// apply BN+ReLU in place to both per-type buffers (uint4 granularity; 8 cols per uint4)
__global__ __launch_bounds__(256) void k_bnapply2(
    uint4* __restrict__ xa, const float* __restrict__ ssa, int qa,
    uint4* __restrict__ xb, const float* __restrict__ ssb, int qb)
{
    int t = blockIdx.x * 256 + threadIdx.x;
    int stride = gridDim.x * 256;
    int total = qa + qb;
    for (; t < total; t += stride) {
        uint4* x; const float* ss; int i;
        if (t < qa) { x = xa; ss = ssa; i = t; }
        else        { x = xb; ss = ssb; i = t - qa; }
        int cb = (i & 7) * 8;
        uint4 u = x[i];
        uint w[4] = {u.x, u.y, u.z, u.w};
        #pragma unroll
        for (int j = 0; j < 4; ++j) {
            float f0 = __uint_as_float(w[j] << 16)         * ss[cb + 2 * j]     + ss[64 + cb + 2 * j];
            float f1 = __uint_as_float(w[j] & 0xffff0000u) * ss[cb + 2 * j + 1] + ss[64 + cb + 2 * j + 1];
            w[j] = pack2(fmaxf(f0, 0.f), fmaxf(f1, 0.f));
        }
        x[i] = make_uint4(w[0], w[1], w[2], w[3]);
    }
}

// ---------------- classifier (inputs already BN'd) ----------------
__global__ __launch_bounds__(256) void k_cls_mfma(
    const ushort* __restrict__ xu, const ushort* __restrict__ xm,
    const int* __restrict__ lsrc, const int* __restrict__ ldst,
    const ushort* __restrict__ wp, const float* __restrict__ b1,
    const float* __restrict__ w2, const float* __restrict__ b2,
    float* __restrict__ out, int L)
{
    int wave = threadIdx.x >> 6, lane = threadIdx.x & 63;
    int l0 = blockIdx.x * 64 + wave * 16;
    if (l0 >= L) return;
    int lrow = lane & 15, lk = lane >> 4;
    int li = l0 + lrow; if (li >= L) li = L - 1;
    const ushort* pu = xu + (size_t)lsrc[li] * HD + lk * 8;
    const ushort* pm = xm + (size_t)ldst[li] * HD + lk * 8;
    const bf16x8* wpv = (const bf16x8*)wp + lane;

    bf16x8 a[4];
    a[0] = *(const bf16x8*)(pu);
    a[1] = *(const bf16x8*)(pu + 32);
    a[2] = *(const bf16x8*)(pm);
    a[3] = *(const bf16x8*)(pm + 32);

    f32x4 acc[4];
    #pragma unroll
    for (int nn = 0; nn < 4; ++nn) acc[nn] = (f32x4){0.f, 0.f, 0.f, 0.f};
    #pragma unroll
    for (int kk = 0; kk < 4; ++kk)
        #pragma unroll
        for (int nn = 0; nn < 4; ++nn)
            acc[nn] = __builtin_amdgcn_mfma_f32_16x16x32_bf16(a[kk], wpv[(kk * 4 + nn) * 64], acc[nn], 0, 0, 0);

    float p0 = 0.f, p1 = 0.f, p2 = 0.f, p3 = 0.f;
    #pragma unroll
    for (int nn = 0; nn < 4; ++nn) {
        int cidx = lrow + 16 * nn;
        float bb = b1[cidx], w = w2[cidx];
        p0 += fmaxf(acc[nn][0] + bb, 0.f) * w;
        p1 += fmaxf(acc[nn][1] + bb, 0.f) * w;
        p2 += fmaxf(acc[nn][2] + bb, 0.f) * w;
        p3 += fmaxf(acc[nn][3] + bb, 0.f) * w;
    }
    #pragma unroll
    for (int off = 1; off < 16; off <<= 1) {
        p0 += __shfl_xor(p0, off);
        p1 += __shfl_xor(p1, off);
        p2 += __shfl_xor(p2, off);
        p3 += __shfl_xor(p3, off);
    }
    if (lrow == 0) {
        float bb2 = b2[0];
        int r0 = l0 + lk * 4;
        if (r0 + 0 < L) out[r0 + 0] = p0 + bb2;
        if (r0 + 1 < L) out[r0 + 1] = p1 + bb2;
        if (r0 + 2 < L) out[r0 + 2] = p2 + bb2;
        if (r0 + 3 < L) out[r0 + 3] = p3 + bb2;
    }
}

extern "C" void kernel_launch(void* const* d_in, const int* in_sizes, int n_in,
                              void* d_out, int out_size, void* d_ws, size_t ws_size,
                              hipStream_t stream) {
    (void)n_in; (void)ws_size;
    const int NU = in_sizes[1] / HD;
    const int NM = in_sizes[2] / HD;
    const int F  = in_sizes[0] / NM;
    const int E  = in_sizes[31];
    const int L  = out_size;
    const int NBm = (NM + (1 << MSH) - 1) >> MSH;
    const int NBu = (NU + (1 << USH) - 1) >> USH;

    int iL0RA, iL0RE, iL1RA, iL1RE, iBN0U, iBN0M, iBN1U, iBN1M;
    if (in_sizes[11] == HD) {          // setup-dict order
        iL0RA = 5; iL0RE = 8; iBN0U = 11; iBN0M = 13;
        iL1RA = 15; iL1RE = 18; iBN1U = 21; iBN1M = 23;
    } else {                           // reference-signature order
        iL0RA = 5; iL0RE = 8; iL1RA = 11; iL1RE = 14;
        iBN0U = 17; iBN0M = 19; iBN1U = 21; iBN1M = 23;
    }
    const float* movie_x   = (const float*)d_in[0];
    const float* user_emb  = (const float*)d_in[1];
    const float* movie_emb = (const float*)d_in[2];
    const float* mlw       = (const float*)d_in[3];
    const float* mlb       = (const float*)d_in[4];
    const float* cls_w1    = (const float*)d_in[25];
    const float* cls_b1    = (const float*)d_in[26];
    const float* cls_w2    = (const float*)d_in[27];
    const float* cls_b2    = (const float*)d_in[28];
    const int* user_node_id  = (const int*)d_in[29];
    const int* movie_node_id = (const int*)d_in[30];
    const int* rates_src   = (const int*)d_in[31];
    const int* rates_dst   = (const int*)d_in[32];
    const int* label_src   = (const int*)d_in[33];
    const int* label_dst   = (const int*)d_in[34];

    // ---- workspace ----
    char* wsb = (char*)d_ws;
    auto alloc = [&](size_t bytes) { char* p = wsb; wsb += (bytes + 255) & ~(size_t)255; return p; };
    ushort* xu_a = (ushort*)alloc((size_t)NU * HD * 2);
    ushort* xu_b = (ushort*)alloc((size_t)NU * HD * 2);
    ushort* xm_a = (ushort*)alloc((size_t)NM * HD * 2);
    ushort* xm_b = (ushort*)alloc((size_t)NM * HD * 2);
    ushort* meanU = (ushort*)alloc((size_t)NU * HD * 2);
    ushort* meanM = (ushort*)alloc((size_t)NM * HD * 2);
    ushort* wp_all = (ushort*)alloc(5 * 8192 * 2);
    int* rp_m = (int*)alloc((size_t)(NM + 1) * 4);
    int* rp_u = (int*)alloc((size_t)(NU + 1) * 4);
    int* nbr_m = (int*)alloc((size_t)E * 4);
    int* nbr_u = (int*)alloc((size_t)E * 4);
    uint* pairs_m = (uint*)alloc((size_t)E * 4);
    uint* pairs_u = (uint*)alloc((size_t)E * 4);
    int* bkrp_m = (int*)alloc(257 * 4);
    int* bkrp_u = (int*)alloc(257 * 4);
    int* bcur_m = (int*)alloc(256 * 4);
    int* bcur_u = (int*)alloc(256 * 4);
    size_t zr_bytes = 2 * 256 * 4 + (size_t)4 * NREP * 128 * 4;
    char* zr = alloc(zr_bytes);
    int* bk_u = (int*)zr;
    int* bk_m = bk_u + 256;
    float* statsAll = (float*)(bk_m + 256);
    float* ss_u0 = (float*)alloc(128 * 4);
    float* ss_m0 = (float*)alloc(128 * 4);
    float* ss_u1 = (float*)alloc(128 * 4);
    float* ss_m1 = (float*)alloc(128 * 4);

    ushort* wp0 = wp_all;              // l0 rev (user stage)
    ushort* wp1 = wp_all + 8192;       // l0 rates (movie stage)
    ushort* wp2 = wp_all + 16384;      // l1 rev
    ushort* wp3 = wp_all + 24576;      // l1 rates
    ushort* wpc = wp_all + 32768;      // classifier
    float* st0 = statsAll;
    float* st1 = statsAll + NREP * 128;
    float* st2 = statsAll + 2 * NREP * 128;
    float* st3 = statsAll + 3 * NREP * 128;

    const int sgrid = (E + CHUNK - 1) / CHUNK;
    const int gridU_r = (NU + 31) / 32, gridM_r = (NM + 31) / 32;
    const int gridU_m = (NU + 63) / 64, gridM_m = (NM + 63) / 64;
    const int gridMF = (NM + 255) / 256;
    const int qU = NU * 8, qM = NM * 8;                  // uint4 counts
    const int gridBA = (qU + qM + 255) / 256;

    hipMemsetAsync(zr, 0, zr_bytes, stream);
    k_pack_all<<<160, 256, 0, stream>>>(
        (const float*)d_in[iL0RE + 0], (const float*)d_in[iL0RE + 2],
        (const float*)d_in[iL0RA + 0], (const float*)d_in[iL0RA + 2],
        (const float*)d_in[iL1RE + 0], (const float*)d_in[iL1RE + 2],
        (const float*)d_in[iL1RA + 0], (const float*)d_in[iL1RA + 2],
        cls_w1, cls_w1 + 64 * 64, wp_all);

    // ---- CSR build (dual-direction, bucket-local) ----
    k_bucket_hist<<<1024, 256, 0, stream>>>(rates_src, rates_dst, bk_u, bk_m, E);
    k_bucket_scan<<<1, 256, 0, stream>>>(bk_u, bk_m, bkrp_u, bkrp_m, bcur_u, bcur_m, NBu, NBm, E);
    k_scatter2<<<sgrid, 256, 0, stream>>>(rates_src, rates_dst, bcur_m, pairs_m, bcur_u, pairs_u, E, NBm, NBu);
    k_finalize2<<<NBm + NBu, 256, 0, stream>>>(pairs_m, bkrp_m, rp_m, nbr_m, NM, NBm,
                                               pairs_u, bkrp_u, rp_u, nbr_u, NU, NBu, E);

    // ---- init node features ----
    k_init2<<<gridMF + 2048, 256, 0, stream>>>(movie_x, mlw, mlb, movie_emb, movie_node_id,
                                               xm_a, NM, F, gridMF, user_emb, user_node_id, xu_a, NU);

    // ---- layer 0 ----
    k_reduce2<<<gridU_r + gridM_r, 256, 0, stream>>>(
        xm_a, rp_u, nbr_u, meanU, NU, gridU_r,
        xu_a, rp_m, nbr_m, meanM, NM);
    k_mfma2<<<gridU_m + gridM_m, 256, 0, stream>>>(
        meanU, xu_a, wp0, (const float*)d_in[iL0RE + 1], xu_b, st0, NU, gridU_m,
        meanM, xm_a, wp1, (const float*)d_in[iL0RA + 1], xm_b, st1, NM);
    k_bnfin2<<<2, 128, 0, stream>>>(
        st0, (const float*)d_in[iBN0U], (const float*)d_in[iBN0U + 1], ss_u0, NU,
        st1, (const float*)d_in[iBN0M], (const float*)d_in[iBN0M + 1], ss_m0, NM);
    k_bnapply2<<<gridBA, 256, 0, stream>>>((uint4*)xu_b, ss_u0, qU, (uint4*)xm_b, ss_m0, qM);

    // ---- layer 1 ----
    k_reduce2<<<gridU_r + gridM_r, 256, 0, stream>>>(
        xm_b, rp_u, nbr_u, meanU, NU, gridU_r,
        xu_b, rp_m, nbr_m, meanM, NM);
    k_mfma2<<<gridU_m + gridM_m, 256, 0, stream>>>(
        meanU, xu_b, wp2, (const float*)d_in[iL1RE + 1], xu_a, st2, NU, gridU_m,
        meanM, xm_b, wp3, (const float*)d_in[iL1RA + 1], xm_a, st3, NM);
    k_bnfin2<<<2, 128, 0, stream>>>(
        st2, (const float*)d_in[iBN1U], (const float*)d_in[iBN1U + 1], ss_u1, NU,
        st3, (const float*)d_in[iBN1M], (const float*)d_in[iBN1M + 1], ss_m1, NM);
    k_bnapply2<<<gridBA, 256, 0, stream>>>((uint4*)xu_a, ss_u1, qU, (uint4*)xm_a, ss_m1, qM);

    // ---- classifier ----
    k_cls_mfma<<<(L + 63) / 64, 256, 0, stream>>>(xu_a, xm_a,
        label_src, label_dst, wpc, cls_b1, cls_w2, cls_b2, (float*)d_out, L);
}

// Round 12
// 227.831 us; speedup vs baseline: 1.7507x; 1.0749x over previous
//
#include <hip/hip_runtime.h>
#include <hip/hip_bf16.h>
#include <stdint.h>

#define HD 64
#define CHUNK 4096
#define EPT 16
#define USH 9            // user bucket shift (512-node buckets)
#define MSH 8            // movie bucket shift (256-node buckets)
#define FCAP 12288
#define VMASK 0x7fffffu  // low 23 bits = value; high bits = node-within-bucket
#define NREP 64          // stats replicas (contention spreading)

typedef __bf16 bf16x8 __attribute__((ext_vector_type(8)));
typedef float f32x4 __attribute__((ext_vector_type(4)));
typedef float f32x2 __attribute__((ext_vector_type(2)));

__device__ __forceinline__ void atomAddF(float* p, float v) { unsafeAtomicAdd(p, v); }
__device__ __forceinline__ ushort f2bf(float v) {
    __hip_bfloat16 h = __float2bfloat16(v);
    return *(ushort*)&h;
}
__device__ __forceinline__ uint pack2(float a, float b) {
    return (uint)f2bf(a) | ((uint)f2bf(b) << 16);
}

// inclusive wave scan (64 lanes)
__device__ __forceinline__ int wave_scan_incl(int v, int lane) {
    #pragma unroll
    for (int off = 1; off < 64; off <<= 1) {
        int x = __shfl_up(v, off);
        if (lane >= off) v += x;
    }
    return v;
}

// ---------------- CSR build (bucket-local) ----------------

__global__ __launch_bounds__(256) void k_bucket_hist(
    const int* __restrict__ src, const int* __restrict__ dst,
    int* __restrict__ bk_u, int* __restrict__ bk_m, int E)
{
    __shared__ int hu[256], hm[256];
    int tid = threadIdx.x;
    hu[tid] = 0; hm[tid] = 0;
    __syncthreads();
    int t = blockIdx.x * 256 + tid;
    int stride = gridDim.x * 256;
    for (; t < E; t += stride) {
        atomicAdd(&hu[src[t] >> USH], 1);
        atomicAdd(&hm[dst[t] >> MSH], 1);
    }
    __syncthreads();
    if (hu[tid]) atomicAdd(&bk_u[tid], hu[tid]);
    if (hm[tid]) atomicAdd(&bk_m[tid], hm[tid]);
}

__global__ void k_bucket_scan(const int* __restrict__ bk_u, const int* __restrict__ bk_m,
                              int* __restrict__ bkrp_u, int* __restrict__ bkrp_m,
                              int* __restrict__ bcur_u, int* __restrict__ bcur_m,
                              int NBu, int NBm, int E)
{
    __shared__ int sh[256];
    int t = threadIdx.x;
    int v = (t < NBu) ? bk_u[t] : 0;
    sh[t] = v; __syncthreads();
    for (int off = 1; off < 256; off <<= 1) {
        int x = (t >= off) ? sh[t - off] : 0;
        __syncthreads(); sh[t] += x; __syncthreads();
    }
    int excl = sh[t] - v;
    if (t < NBu) { bkrp_u[t] = excl; bcur_u[t] = excl; }
    if (t == NBu) bkrp_u[t] = E;
    __syncthreads();
    v = (t < NBm) ? bk_m[t] : 0;
    sh[t] = v; __syncthreads();
    for (int off = 1; off < 256; off <<= 1) {
        int x = (t >= off) ? sh[t - off] : 0;
        __syncthreads(); sh[t] += x; __syncthreads();
    }
    excl = sh[t] - v;
    if (t < NBm) { bkrp_m[t] = excl; bcur_m[t] = excl; }
    if (t == NBm) bkrp_m[t] = E;
}

// one phase of the dual scatter (keys/vals already in registers)
__device__ __forceinline__ void scatter_phase(
    const int* kk, const int* vv, int sh, int NB,
    int* __restrict__ bcur, uint* __restrict__ pairs, int E, int base, int tid,
    int* lcnt, int* lstart, int* gbase, int* wsum, uint2* lpair)
{
    lcnt[tid] = 0;
    __syncthreads();
    int ofs[EPT];
    #pragma unroll
    for (int i = 0; i < EPT; ++i)
        if (kk[i] >= 0) ofs[i] = atomicAdd(&lcnt[kk[i] >> sh], 1);
    __syncthreads();
    int c = lcnt[tid];
    int lane = tid & 63, wv = tid >> 6;
    int incl = wave_scan_incl(c, lane);
    if (lane == 63) wsum[wv] = incl;
    if (c > 0 && tid < NB) gbase[tid] = atomicAdd(&bcur[tid], c);
    __syncthreads();
    int prefix = 0;
    #pragma unroll
    for (int w = 0; w < 4; ++w) if (w < wv) prefix += wsum[w];
    lstart[tid] = prefix + incl - c;
    __syncthreads();
    #pragma unroll
    for (int i = 0; i < EPT; ++i)
        if (kk[i] >= 0) {
            int b = kk[i] >> sh;
            lpair[lstart[b] + ofs[i]] = make_uint2((uint)kk[i], (uint)vv[i]);
        }
    __syncthreads();
    int total = E - base; if (total > CHUNK) total = CHUNK;
    uint bmask = (1u << sh) - 1u;
    for (int j = tid; j < total; j += 256) {
        uint2 p = lpair[j];
        int b = (int)(p.x >> sh);
        pairs[gbase[b] + (j - lstart[b])] = ((p.x & bmask) << 23) | p.y;
    }
}

// dual-direction scatter: load (src,dst) once, bucket both ways
__global__ __launch_bounds__(256) void k_scatter2(
    const int* __restrict__ srcA, const int* __restrict__ dstA,
    int* __restrict__ bcur_m, uint* __restrict__ pairs_m,
    int* __restrict__ bcur_u, uint* __restrict__ pairs_u,
    int E, int NBm, int NBu)
{
    __shared__ int lcnt[256], lstart[256], gbase[256], wsum[4];
    __shared__ uint2 lpair[CHUNK];
    int tid = threadIdx.x;
    int base = blockIdx.x * CHUNK;
    int ssr[EPT], ddr[EPT];
    #pragma unroll
    for (int i = 0; i < EPT; ++i) {
        int idx = base + i * 256 + tid;
        bool ok = idx < E;
        ssr[i] = ok ? srcA[idx] : -1;
        ddr[i] = ok ? dstA[idx] : -1;
    }
    scatter_phase(ddr, ssr, MSH, NBm, bcur_m, pairs_m, E, base, tid, lcnt, lstart, gbase, wsum, lpair);
    __syncthreads();
    scatter_phase(ssr, ddr, USH, NBu, bcur_u, pairs_u, E, base, tid, lcnt, lstart, gbase, wsum, lpair);
}

__device__ __forceinline__ void finalize_body(
    const uint* __restrict__ pairs, const int* __restrict__ bkrp,
    int* __restrict__ rp, int* __restrict__ nbr,
    int N, int E, int sh, int b, int NB, int tid,
    int* lcnt, int* lsc, uint* lp)
{
    int base = b << sh;
    int rs = bkrp[b], re = bkrp[b + 1];
    int cnt = re - rs;
    bool staged = cnt <= FCAP;
    lcnt[tid] = 0; lcnt[tid + 256] = 0;
    __syncthreads();
    if (staged) {
        for (int j = tid; j < cnt; j += 256) {
            uint p = pairs[rs + j];
            lp[j] = p;
            atomicAdd(&lcnt[p >> 23], 1);
        }
    } else {
        for (int j = rs + tid; j < re; j += 256)
            atomicAdd(&lcnt[pairs[j] >> 23], 1);
    }
    __syncthreads();
    int c0 = lcnt[2 * tid], c1 = lcnt[2 * tid + 1];
    int s = c0 + c1;
    int lane = tid & 63, wv = tid >> 6;
    int incl = wave_scan_incl(s, lane);
    if (lane == 63) lsc[wv] = incl;
    __syncthreads();
    int prefix = 0;
    #pragma unroll
    for (int w = 0; w < 4; ++w) if (w < wv) prefix += lsc[w];
    int excl = prefix + incl - s;
    int nbn = N - base; int bsz = 1 << sh; if (nbn > bsz) nbn = bsz;
    if (2 * tid < nbn)     rp[base + 2 * tid]     = rs + excl;
    if (2 * tid + 1 < nbn) rp[base + 2 * tid + 1] = rs + excl + c0;
    if (b == NB - 1 && tid == 0) rp[N] = E;
    __syncthreads();
    lcnt[2 * tid] = excl;
    lcnt[2 * tid + 1] = excl + c0;
    __syncthreads();
    if (staged) {
        for (int j = tid; j < cnt; j += 256) {
            uint p = lp[j];
            int pos = rs + atomicAdd(&lcnt[p >> 23], 1);
            nbr[pos] = (int)(p & VMASK);
        }
    } else {
        for (int j = rs + tid; j < re; j += 256) {
            uint p = pairs[j];
            int pos = rs + atomicAdd(&lcnt[p >> 23], 1);
            nbr[pos] = (int)(p & VMASK);
        }
    }
}

// combined finalize for both directions: blocks [0,NBm) movie, [NBm, NBm+NBu) user
__global__ __launch_bounds__(256) void k_finalize2(
    const uint* __restrict__ pairs_m, const int* __restrict__ bkrp_m,
    int* __restrict__ rp_m, int* __restrict__ nbr_m, int NM, int NBm,
    const uint* __restrict__ pairs_u, const int* __restrict__ bkrp_u,
    int* __restrict__ rp_u, int* __restrict__ nbr_u, int NU, int NBu, int E)
{
    __shared__ int lcnt[512];
    __shared__ int lsc[4];
    __shared__ uint lp[FCAP];
    int b = blockIdx.x, tid = threadIdx.x;
    if (b < NBm)
        finalize_body(pairs_m, bkrp_m, rp_m, nbr_m, NM, E, MSH, b, NBm, tid, lcnt, lsc, lp);
    else
        finalize_body(pairs_u, bkrp_u, rp_u, nbr_u, NU, E, USH, b - NBm, NBu, tid, lcnt, lsc, lp);
}

// ---------------- weight fragment packing (5 matrices, one kernel) ----------------
__global__ void k_pack_all(const float* __restrict__ w0lo, const float* __restrict__ w0hi,
                           const float* __restrict__ w1lo, const float* __restrict__ w1hi,
                           const float* __restrict__ w2lo, const float* __restrict__ w2hi,
                           const float* __restrict__ w3lo, const float* __restrict__ w3hi,
                           const float* __restrict__ w4lo, const float* __restrict__ w4hi,
                           ushort* __restrict__ dst) {
    int t = blockIdx.x * blockDim.x + threadIdx.x;   // 40960 threads
    int mid = t >> 13, r = t & 8191;
    const float* lo; const float* hi;
    switch (mid) {
        case 0: lo = w0lo; hi = w0hi; break;
        case 1: lo = w1lo; hi = w1hi; break;
        case 2: lo = w2lo; hi = w2hi; break;
        case 3: lo = w3lo; hi = w3hi; break;
        default: lo = w4lo; hi = w4hi;
    }
    int e = r & 7, lane = (r >> 3) & 63, nn = (r >> 9) & 3, kk = r >> 11;
    int k = (lane >> 4) * 8 + e + 32 * kk;
    int col = (lane & 15) + 16 * nn;
    float v = (k < 64) ? lo[k * 64 + col] : hi[(k - 64) * 64 + col];
    dst[t] = f2bf(v);
}

// ---------------- combined init: movie_feat blocks then gather_rows blocks ----------------
__global__ __launch_bounds__(256) void k_init2(
    const float* __restrict__ mx, const float* __restrict__ W,
    const float* __restrict__ b, const float* __restrict__ memb,
    const int* __restrict__ mids, ushort* __restrict__ xm, int NM, int F, int gridMF,
    const float* __restrict__ uemb, const int* __restrict__ uids,
    ushort* __restrict__ xu, int NU)
{
    if ((int)blockIdx.x < gridMF) {
        int m = blockIdx.x * 256 + threadIdx.x;
        if (m >= NM) return;
        const float* xr = mx + (size_t)m * F;
        float acc[HD];
        #pragma unroll
        for (int j = 0; j < HD; ++j) acc[j] = b[j];
        for (int f = 0; f < F; ++f) {
            float v = xr[f];
            #pragma unroll
            for (int j = 0; j < HD; ++j) acc[j] += v * W[f * HD + j];
        }
        int nid = mids[m];
        const float* er = memb + (size_t)nid * HD;
        uint* o = (uint*)(xm + (size_t)m * HD);
        #pragma unroll
        for (int j = 0; j < HD; j += 2)
            o[j >> 1] = pack2(acc[j] + er[j], acc[j + 1] + er[j + 1]);
    } else {
        int t = (blockIdx.x - gridMF) * 256 + threadIdx.x;
        int total = NU * HD;
        int stride = (gridDim.x - gridMF) * 256;
        for (; t < total; t += stride) {
            int i = t >> 6, h = t & 63;
            xu[t] = f2bf(uemb[(size_t)uids[i] * HD + h]);
        }
    }
}

// ---------------- combined segmented mean: 8-lane slots, uint4 rows, unroll 4 ----------------
__device__ __forceinline__ void acc_u4(f32x2* acc, uint4 u) {
    uint w[4] = {u.x, u.y, u.z, u.w};
    #pragma unroll
    for (int i = 0; i < 4; ++i)
        acc[i] += (f32x2){__uint_as_float(w[i] << 16), __uint_as_float(w[i] & 0xffff0000u)};
}

__global__ __launch_bounds__(256) void k_reduce2(
    const ushort* __restrict__ xsU, const int* __restrict__ rpU,
    const int* __restrict__ nbrU, ushort* __restrict__ meanU, int NU, int gridU,
    const ushort* __restrict__ xsM, const int* __restrict__ rpM,
    const int* __restrict__ nbrM, ushort* __restrict__ meanM, int NM)
{
    int bid = blockIdx.x;
    const ushort* xsrc; const int* rp; const int* nbr; ushort* mean; int N; int sb;
    if (bid < gridU) { xsrc = xsU; rp = rpU; nbr = nbrU; mean = meanU; N = NU; sb = bid; }
    else             { xsrc = xsM; rp = rpM; nbr = nbrM; mean = meanM; N = NM; sb = bid - gridU; }
    int slot = sb * 32 + (threadIdx.x >> 3);
    if (slot >= N) return;
    uint l = threadIdx.x & 7;
    const uint4* xs = (const uint4*)xsrc;
    int s0 = rp[slot], s1 = rp[slot + 1];
    f32x2 acc[4];
    #pragma unroll
    for (int i = 0; i < 4; ++i) acc[i] = (f32x2){0.f, 0.f};
    int k = s0;
    for (; k + 4 <= s1; k += 4) {
        uint n0 = (uint)nbr[k], n1 = (uint)nbr[k + 1];
        uint n2 = (uint)nbr[k + 2], n3 = (uint)nbr[k + 3];
        uint4 u0 = xs[(n0 << 3) + l];
        uint4 u1 = xs[(n1 << 3) + l];
        uint4 u2 = xs[(n2 << 3) + l];
        uint4 u3 = xs[(n3 << 3) + l];
        acc_u4(acc, u0);
        acc_u4(acc, u1);
        acc_u4(acc, u2);
        acc_u4(acc, u3);
    }
    for (; k < s1; ++k) acc_u4(acc, xs[((uint)nbr[k] << 3) + l]);
    float inv = (s1 > s0) ? 1.f / (float)(s1 - s0) : 0.f;
    uint4 o;
    o.x = pack2(acc[0].x * inv, acc[0].y * inv);
    o.y = pack2(acc[1].x * inv, acc[1].y * inv);
    o.z = pack2(acc[2].x * inv, acc[2].y * inv);
    o.w = pack2(acc[3].x * inv, acc[3].y * inv);
    ((uint4*)mean)[((uint)slot << 3) + l] = o;
}

// ---------------- MFMA (multi-pass: 256 nodes/block, B-fragments loaded once) ----------------
__device__ __forceinline__ void mfma_body(
    const ushort* __restrict__ meanb, const ushort* __restrict__ xdst,
    const ushort* __restrict__ wp, const float* __restrict__ blv,
    ushort* __restrict__ out, float* __restrict__ stats, int N, int blk, int tid,
    float* lsum, float* lsq)
{
    if (tid < 64) { lsum[tid] = 0.f; lsq[tid] = 0.f; }
    __syncthreads();
    int wave = tid >> 6, lane = tid & 63;
    int lrow = lane & 15, lk = lane >> 4;
    const bf16x8* wpv = (const bf16x8*)wp + lane;

    bf16x8 b[4][4];
    #pragma unroll
    for (int kk = 0; kk < 4; ++kk)
        #pragma unroll
        for (int nn = 0; nn < 4; ++nn)
            b[kk][nn] = wpv[(kk * 4 + nn) * 64];

    float bias[4];
    #pragma unroll
    for (int nn = 0; nn < 4; ++nn) bias[nn] = blv[lrow + 16 * nn];

    float ssum[4] = {0.f, 0.f, 0.f, 0.f}, ssq[4] = {0.f, 0.f, 0.f, 0.f};
    int nbase = blk * 256 + wave * 64;

    #pragma unroll
    for (int p = 0; p < 4; ++p) {
        int n0 = nbase + p * 16;
        if (n0 < N) {
            int arow = n0 + lrow; if (arow >= N) arow = N - 1;
            const ushort* pm = meanb + (size_t)arow * HD + lk * 8;
            const ushort* px = xdst  + (size_t)arow * HD + lk * 8;
            bf16x8 a[4];
            a[0] = *(const bf16x8*)(pm);
            a[1] = *(const bf16x8*)(pm + 32);
            a[2] = *(const bf16x8*)(px);
            a[3] = *(const bf16x8*)(px + 32);

            f32x4 acc[4];
            #pragma unroll
            for (int nn = 0; nn < 4; ++nn) acc[nn] = (f32x4){0.f, 0.f, 0.f, 0.f};
            #pragma unroll
            for (int kk = 0; kk < 4; ++kk)
                #pragma unroll
                for (int nn = 0; nn < 4; ++nn)
                    acc[nn] = __builtin_amdgcn_mfma_f32_16x16x32_bf16(a[kk], b[kk][nn], acc[nn], 0, 0, 0);

            #pragma unroll
            for (int nn = 0; nn < 4; ++nn) {
                #pragma unroll
                for (int r = 0; r < 4; ++r) {
                    int orow = n0 + lk * 4 + r;
                    float v = acc[nn][r] + bias[nn];
                    bool ok = orow < N;
                    if (ok) out[(size_t)orow * HD + lrow + 16 * nn] = f2bf(v);
                    float vv = ok ? v : 0.f;
                    ssum[nn] += vv; ssq[nn] += vv * vv;
                }
            }
        }
    }

    #pragma unroll
    for (int nn = 0; nn < 4; ++nn) {
        float s = ssum[nn], q = ssq[nn];
        s += __shfl_xor(s, 16); s += __shfl_xor(s, 32);
        q += __shfl_xor(q, 16); q += __shfl_xor(q, 32);
        if (lk == 0) {
            atomAddF(&lsum[lrow + 16 * nn], s);
            atomAddF(&lsq[lrow + 16 * nn], q);
        }
    }
    __syncthreads();
    float* st = stats + (size_t)(blk & (NREP - 1)) * 128;
    if (tid < 64) {
        atomAddF(&st[tid], lsum[tid]);
        atomAddF(&st[64 + tid], lsq[tid]);
    }
}

__global__ __launch_bounds__(256) void k_mfma2(
    const ushort* __restrict__ meanU, const ushort* __restrict__ xuD,
    const ushort* __restrict__ wpU, const float* __restrict__ blU,
    ushort* __restrict__ outU, float* __restrict__ stU, int NU, int gridU,
    const ushort* __restrict__ meanM, const ushort* __restrict__ xmD,
    const ushort* __restrict__ wpM, const float* __restrict__ blM,
    ushort* __restrict__ outM, float* __restrict__ stM, int NM)
{
    __shared__ float lsum[64], lsq[64];
    int bid = blockIdx.x, tid = threadIdx.x;
    if (bid < gridU)
        mfma_body(meanU, xuD, wpU, blU, outU, stU, NU, bid, tid, lsum, lsq);
    else
        mfma_body(meanM, xmD, wpM, blM, outM, stM, NM, bid - gridU, tid, lsum, lsq);
}

// combined BN finalize: block 0 = user, block 1 = movie
__global__ void k_bnfin2(const float* __restrict__ stA, const float* __restrict__ gA,
                         const float* __restrict__ bA, float* __restrict__ ssA, int NA,
                         const float* __restrict__ stB, const float* __restrict__ gB,
                         const float* __restrict__ bB, float* __restrict__ ssB, int NB_)
{
    __shared__ float red[128];
    const float* stats; const float* g; const float* b; float* ss; int N;
    if (blockIdx.x == 0) { stats = stA; g = gA; b = bA; ss = ssA; N = NA; }
    else                 { stats = stB; g = gB; b = bB; ss = ssB; N = NB_; }
    int j = threadIdx.x;   // 0..127
    float s = 0.f;
    #pragma unroll 8
    for (int r = 0; r < NREP; ++r) s += stats[r * 128 + j];
    red[j] = s;
    __syncthreads();
    if (j < HD) {
        float invN = 1.f / (float)N;
        float mu = red[j] * invN;
        float var = red[HD + j] * invN - mu * mu;
        var = var < 0.f ? 0.f : var;
        float sc = g[j] * rsqrtf(var + 1e-5f);
        ss[j] = sc;
        ss[HD + j] = b[j] - mu * sc;
    }
}

// apply BN+ReLU in place to both per-type buffers (uint4 granularity; 8 cols per uint4)
__global__ __launch_bounds__(256) void k_bnapply2(
    uint4* __restrict__ xa, const float* __restrict__ ssa, int qa,
    uint4* __restrict__ xb, const float* __restrict__ ssb, int qb)
{
    int t = blockIdx.x * 256 + threadIdx.x;
    int stride = gridDim.x * 256;
    int total = qa + qb;
    for (; t < total; t += stride) {
        uint4* x; const float* ss; int i;
        if (t < qa) { x = xa; ss = ssa; i = t; }
        else        { x = xb; ss = ssb; i = t - qa; }
        int cb = (i & 7) * 8;
        uint4 u = x[i];
        uint w[4] = {u.x, u.y, u.z, u.w};
        #pragma unroll
        for (int j = 0; j < 4; ++j) {
            float f0 = __uint_as_float(w[j] << 16)         * ss[cb + 2 * j]     + ss[64 + cb + 2 * j];
            float f1 = __uint_as_float(w[j] & 0xffff0000u) * ss[cb + 2 * j + 1] + ss[64 + cb + 2 * j + 1];
            w[j] = pack2(fmaxf(f0, 0.f), fmaxf(f1, 0.f));
        }
        x[i] = make_uint4(w[0], w[1], w[2], w[3]);
    }
}

// ---------------- classifier (multi-pass: 256 labels/block, B loaded once) ----------------
__global__ __launch_bounds__(256) void k_cls_mfma(
    const ushort* __restrict__ xu, const ushort* __restrict__ xm,
    const int* __restrict__ lsrc, const int* __restrict__ ldst,
    const ushort* __restrict__ wp, const float* __restrict__ b1,
    const float* __restrict__ w2, const float* __restrict__ b2,
    float* __restrict__ out, int L)
{
    int wave = threadIdx.x >> 6, lane = threadIdx.x & 63;
    int lbase = blockIdx.x * 256 + wave * 64;
    if (lbase >= L) return;
    int lrow = lane & 15, lk = lane >> 4;
    const bf16x8* wpv = (const bf16x8*)wp + lane;

    bf16x8 b[4][4];
    #pragma unroll
    for (int kk = 0; kk < 4; ++kk)
        #pragma unroll
        for (int nn = 0; nn < 4; ++nn)
            b[kk][nn] = wpv[(kk * 4 + nn) * 64];

    float bb1[4], ww2[4];
    #pragma unroll
    for (int nn = 0; nn < 4; ++nn) {
        bb1[nn] = b1[lrow + 16 * nn];
        ww2[nn] = w2[lrow + 16 * nn];
    }
    float bb2 = b2[0];

    #pragma unroll
    for (int p = 0; p < 4; ++p) {
        int l0 = lbase + p * 16;
        if (l0 >= L) break;
        int li = l0 + lrow; if (li >= L) li = L - 1;
        const ushort* pu = xu + (size_t)lsrc[li] * HD + lk * 8;
        const ushort* pm = xm + (size_t)ldst[li] * HD + lk * 8;
        bf16x8 a[4];
        a[0] = *(const bf16x8*)(pu);
        a[1] = *(const bf16x8*)(pu + 32);
        a[2] = *(const bf16x8*)(pm);
        a[3] = *(const bf16x8*)(pm + 32);

        f32x4 acc[4];
        #pragma unroll
        for (int nn = 0; nn < 4; ++nn) acc[nn] = (f32x4){0.f, 0.f, 0.f, 0.f};
        #pragma unroll
        for (int kk = 0; kk < 4; ++kk)
            #pragma unroll
            for (int nn = 0; nn < 4; ++nn)
                acc[nn] = __builtin_amdgcn_mfma_f32_16x16x32_bf16(a[kk], b[kk][nn], acc[nn], 0, 0, 0);

        float p0 = 0.f, p1 = 0.f, p2 = 0.f, p3 = 0.f;
        #pragma unroll
        for (int nn = 0; nn < 4; ++nn) {
            p0 += fmaxf(acc[nn][0] + bb1[nn], 0.f) * ww2[nn];
            p1 += fmaxf(acc[nn][1] + bb1[nn], 0.f) * ww2[nn];
            p2 += fmaxf(acc[nn][2] + bb1[nn], 0.f) * ww2[nn];
            p3 += fmaxf(acc[nn][3] + bb1[nn], 0.f) * ww2[nn];
        }
        #pragma unroll
        for (int off = 1; off < 16; off <<= 1) {
            p0 += __shfl_xor(p0, off);
            p1 += __shfl_xor(p1, off);
            p2 += __shfl_xor(p2, off);
            p3 += __shfl_xor(p3, off);
        }
        if (lrow == 0) {
            int r0 = l0 + lk * 4;
            if (r0 + 0 < L) out[r0 + 0] = p0 + bb2;
            if (r0 + 1 < L) out[r0 + 1] = p1 + bb2;
            if (r0 + 2 < L) out[r0 + 2] = p2 + bb2;
            if (r0 + 3 < L) out[r0 + 3] = p3 + bb2;
        }
    }
}

extern "C" void kernel_launch(void* const* d_in, const int* in_sizes, int n_in,
                              void* d_out, int out_size, void* d_ws, size_t ws_size,
                              hipStream_t stream) {
    (void)n_in; (void)ws_size;
    const int NU = in_sizes[1] / HD;
    const int NM = in_sizes[2] / HD;
    const int F  = in_sizes[0] / NM;
    const int E  = in_sizes[31];
    const int L  = out_size;
    const int NBm = (NM + (1 << MSH) - 1) >> MSH;
    const int NBu = (NU + (1 << USH) - 1) >> USH;

    int iL0RA, iL0RE, iL1RA, iL1RE, iBN0U, iBN0M, iBN1U, iBN1M;
    if (in_sizes[11] == HD) {          // setup-dict order
        iL0RA = 5; iL0RE = 8; iBN0U = 11; iBN0M = 13;
        iL1RA = 15; iL1RE = 18; iBN1U = 21; iBN1M = 23;
    } else {                           // reference-signature order
        iL0RA = 5; iL0RE = 8; iL1RA = 11; iL1RE = 14;
        iBN0U = 17; iBN0M = 19; iBN1U = 21; iBN1M = 23;
    }
    const float* movie_x   = (const float*)d_in[0];
    const float* user_emb  = (const float*)d_in[1];
    const float* movie_emb = (const float*)d_in[2];
    const float* mlw       = (const float*)d_in[3];
    const float* mlb       = (const float*)d_in[4];
    const float* cls_w1    = (const float*)d_in[25];
    const float* cls_b1    = (const float*)d_in[26];
    const float* cls_w2    = (const float*)d_in[27];
    const float* cls_b2    = (const float*)d_in[28];
    const int* user_node_id  = (const int*)d_in[29];
    const int* movie_node_id = (const int*)d_in[30];
    const int* rates_src   = (const int*)d_in[31];
    const int* rates_dst   = (const int*)d_in[32];
    const int* label_src   = (const int*)d_in[33];
    const int* label_dst   = (const int*)d_in[34];

    // ---- workspace ----
    char* wsb = (char*)d_ws;
    auto alloc = [&](size_t bytes) { char* p = wsb; wsb += (bytes + 255) & ~(size_t)255; return p; };
    ushort* xu_a = (ushort*)alloc((size_t)NU * HD * 2);
    ushort* xu_b = (ushort*)alloc((size_t)NU * HD * 2);
    ushort* xm_a = (ushort*)alloc((size_t)NM * HD * 2);
    ushort* xm_b = (ushort*)alloc((size_t)NM * HD * 2);
    ushort* meanU = (ushort*)alloc((size_t)NU * HD * 2);
    ushort* meanM = (ushort*)alloc((size_t)NM * HD * 2);
    ushort* wp_all = (ushort*)alloc(5 * 8192 * 2);
    int* rp_m = (int*)alloc((size_t)(NM + 1) * 4);
    int* rp_u = (int*)alloc((size_t)(NU + 1) * 4);
    int* nbr_m = (int*)alloc((size_t)E * 4);
    int* nbr_u = (int*)alloc((size_t)E * 4);
    uint* pairs_m = (uint*)alloc((size_t)E * 4);
    uint* pairs_u = (uint*)alloc((size_t)E * 4);
    int* bkrp_m = (int*)alloc(257 * 4);
    int* bkrp_u = (int*)alloc(257 * 4);
    int* bcur_m = (int*)alloc(256 * 4);
    int* bcur_u = (int*)alloc(256 * 4);
    size_t zr_bytes = 2 * 256 * 4 + (size_t)4 * NREP * 128 * 4;
    char* zr = alloc(zr_bytes);
    int* bk_u = (int*)zr;
    int* bk_m = bk_u + 256;
    float* statsAll = (float*)(bk_m + 256);
    float* ss_u0 = (float*)alloc(128 * 4);
    float* ss_m0 = (float*)alloc(128 * 4);
    float* ss_u1 = (float*)alloc(128 * 4);
    float* ss_m1 = (float*)alloc(128 * 4);

    ushort* wp0 = wp_all;              // l0 rev (user stage)
    ushort* wp1 = wp_all + 8192;       // l0 rates (movie stage)
    ushort* wp2 = wp_all + 16384;      // l1 rev
    ushort* wp3 = wp_all + 24576;      // l1 rates
    ushort* wpc = wp_all + 32768;      // classifier
    float* st0 = statsAll;
    float* st1 = statsAll + NREP * 128;
    float* st2 = statsAll + 2 * NREP * 128;
    float* st3 = statsAll + 3 * NREP * 128;

    const int sgrid = (E + CHUNK - 1) / CHUNK;
    const int gridU_r = (NU + 31) / 32, gridM_r = (NM + 31) / 32;
    const int gridU_m = (NU + 255) / 256, gridM_m = (NM + 255) / 256;
    const int gridMF = (NM + 255) / 256;
    const int qU = NU * 8, qM = NM * 8;                  // uint4 counts
    const int gridBA = (qU + qM + 255) / 256;

    hipMemsetAsync(zr, 0, zr_bytes, stream);
    k_pack_all<<<160, 256, 0, stream>>>(
        (const float*)d_in[iL0RE + 0], (const float*)d_in[iL0RE + 2],
        (const float*)d_in[iL0RA + 0], (const float*)d_in[iL0RA + 2],
        (const float*)d_in[iL1RE + 0], (const float*)d_in[iL1RE + 2],
        (const float*)d_in[iL1RA + 0], (const float*)d_in[iL1RA + 2],
        cls_w1, cls_w1 + 64 * 64, wp_all);

    // ---- CSR build (dual-direction, bucket-local) ----
    k_bucket_hist<<<1024, 256, 0, stream>>>(rates_src, rates_dst, bk_u, bk_m, E);
    k_bucket_scan<<<1, 256, 0, stream>>>(bk_u, bk_m, bkrp_u, bkrp_m, bcur_u, bcur_m, NBu, NBm, E);
    k_scatter2<<<sgrid, 256, 0, stream>>>(rates_src, rates_dst, bcur_m, pairs_m, bcur_u, pairs_u, E, NBm, NBu);
    k_finalize2<<<NBm + NBu, 256, 0, stream>>>(pairs_m, bkrp_m, rp_m, nbr_m, NM, NBm,
                                               pairs_u, bkrp_u, rp_u, nbr_u, NU, NBu, E);

    // ---- init node features ----
    k_init2<<<gridMF + 2048, 256, 0, stream>>>(movie_x, mlw, mlb, movie_emb, movie_node_id,
                                               xm_a, NM, F, gridMF, user_emb, user_node_id, xu_a, NU);

    // ---- layer 0 ----
    k_reduce2<<<gridU_r + gridM_r, 256, 0, stream>>>(
        xm_a, rp_u, nbr_u, meanU, NU, gridU_r,
        xu_a, rp_m, nbr_m, meanM, NM);
    k_mfma2<<<gridU_m + gridM_m, 256, 0, stream>>>(
        meanU, xu_a, wp0, (const float*)d_in[iL0RE + 1], xu_b, st0, NU, gridU_m,
        meanM, xm_a, wp1, (const float*)d_in[iL0RA + 1], xm_b, st1, NM);
    k_bnfin2<<<2, 128, 0, stream>>>(
        st0, (const float*)d_in[iBN0U], (const float*)d_in[iBN0U + 1], ss_u0, NU,
        st1, (const float*)d_in[iBN0M], (const float*)d_in[iBN0M + 1], ss_m0, NM);
    k_bnapply2<<<gridBA, 256, 0, stream>>>((uint4*)xu_b, ss_u0, qU, (uint4*)xm_b, ss_m0, qM);

    // ---- layer 1 ----
    k_reduce2<<<gridU_r + gridM_r, 256, 0, stream>>>(
        xm_b, rp_u, nbr_u, meanU, NU, gridU_r,
        xu_b, rp_m, nbr_m, meanM, NM);
    k_mfma2<<<gridU_m + gridM_m, 256, 0, stream>>>(
        meanU, xu_b, wp2, (const float*)d_in[iL1RE + 1], xu_a, st2, NU, gridU_m,
        meanM, xm_b, wp3, (const float*)d_in[iL1RA + 1], xm_a, st3, NM);
    k_bnfin2<<<2, 128, 0, stream>>>(
        st2, (const float*)d_in[iBN1U], (const float*)d_in[iBN1U + 1], ss_u1, NU,
        st3, (const float*)d_in[iBN1M], (const float*)d_in[iBN1M + 1], ss_m1, NM);
    k_bnapply2<<<gridBA, 256, 0, stream>>>((uint4*)xu_a, ss_u1, qU, (uint4*)xm_a, ss_m1, qM);

    // ---- classifier ----
    k_cls_mfma<<<(L + 255) / 256, 256, 0, stream>>>(xu_a, xm_a,
        label_src, label_dst, wpc, cls_b1, cls_w2, cls_b2, (float*)d_out, L);
}